// Round 1
// baseline (345.802 us; speedup 1.0000x reference)
//
#include <hip/hip_runtime.h>
#include <math.h>

#define PI_F 3.14159265358979323846f

__device__ __constant__ float c_EX[8] = {5.447178f, 0.8245472f, 0.1831916f, 1.0f,
                                         5.447178f, 0.8245472f, 0.1831916f, 1.0f};
__device__ __constant__ float c_CF[8] = {0.156285f, 0.904691f, 1.0f, 0.0f,
                                         0.156285f, 0.904691f, 1.0f, 0.0f};

// Boys function F0 replica of reference _f0
__device__ __forceinline__ float f0f(float t) {
    float ts = fmaxf(t, 1e-12f);
    float st = sqrtf(ts);
    float big = 0.5f * sqrtf(PI_F / ts) * erff(st);
    return (t < 1e-10f) ? (1.0f - t * (1.0f / 3.0f)) : big;
}

// One Jacobi rotation at compile-time (p,q); operates on A (symmetric, in regs)
// and accumulates eigenvectors into Vv columns. Branchless.
#define ROT(p, q) do {                                                          \
    float apq = A[p][q];                                                        \
    float diff = A[q][q] - A[p][p];                                             \
    float theta = 0.5f * diff / apq;                                            \
    float tt = copysignf(1.0f, theta) / (fabsf(theta) + sqrtf(1.0f + theta * theta)); \
    tt = (apq == 0.0f) ? 0.0f : tt;                                             \
    float cr = rsqrtf(1.0f + tt * tt);                                          \
    float sr = tt * cr;                                                         \
    _Pragma("unroll")                                                           \
    for (int k_ = 0; k_ < 4; ++k_) { float a1 = A[k_][p], a2 = A[k_][q];        \
        A[k_][p] = cr * a1 - sr * a2; A[k_][q] = sr * a1 + cr * a2; }           \
    _Pragma("unroll")                                                           \
    for (int k_ = 0; k_ < 4; ++k_) { float a1 = A[p][k_], a2 = A[q][k_];        \
        A[p][k_] = cr * a1 - sr * a2; A[q][k_] = sr * a1 + cr * a2; }           \
    _Pragma("unroll")                                                           \
    for (int k_ = 0; k_ < 4; ++k_) { float a1 = Vv[k_][p], a2 = Vv[k_][q];      \
        Vv[k_][p] = cr * a1 - sr * a2; Vv[k_][q] = sr * a1 + cr * a2; }         \
} while (0)

__device__ __forceinline__ void eigh4(float A[4][4], float Vv[4][4], float w[4]) {
    #pragma unroll
    for (int i = 0; i < 4; ++i)
        #pragma unroll
        for (int j = 0; j < 4; ++j) Vv[i][j] = (i == j) ? 1.0f : 0.0f;
    for (int sw = 0; sw < 6; ++sw) {
        ROT(0, 1); ROT(0, 2); ROT(0, 3); ROT(1, 2); ROT(1, 3); ROT(2, 3);
    }
    #pragma unroll
    for (int i = 0; i < 4; ++i) w[i] = A[i][i];
}

// Fock build from density D (regs) and antisymmetrized ERI table in LDS.
#define BUILD_F() do {                                                          \
    _Pragma("unroll")                                                           \
    for (int i_ = 0; i_ < 4; ++i_)                                              \
    _Pragma("unroll")                                                           \
    for (int j_ = 0; j_ < 4; ++j_) {                                            \
        float s_ = 0.0f;                                                        \
        _Pragma("unroll")                                                       \
        for (int k_ = 0; k_ < 4; ++k_)                                          \
        _Pragma("unroll")                                                       \
        for (int l_ = 0; l_ < 4; ++l_)                                          \
            s_ += D[k_][l_] * sFk[i_ * 64 + j_ * 16 + k_ * 4 + l_];             \
        F[i_][j_] = Hc[i_][j_] + s_;                                            \
    }                                                                           \
} while (0)

__global__ __launch_bounds__(64) void hf_h2_kernel(const float* __restrict__ R,
                                                   float* __restrict__ out) {
    // primitive-pair tables (64 pairs = 8 prims x 8 prims)
    __shared__ float pp[64], pK[64], pPx[64], pPy[64], pPz[64], pcc[64];
    __shared__ float pSp[64], pTp[64], pVp[64];
    __shared__ float sSm[16], sTm[16], sVm[16], sHc[16], sN[4];
    __shared__ float sERI[256], sFk[256];

    const int lane = threadIdx.x;

    // ---- Phase 1: per primitive-pair quantities ----
    {
        int u = lane >> 3, v = lane & 7;
        float au = c_EX[u], av = c_EX[v];
        float cu = c_CF[u] * powf(2.0f * au / PI_F, 0.75f);
        float cv = c_CF[v] * powf(2.0f * av / PI_F, 0.75f);
        int atu = (u >> 2) * 3, atv = (v >> 2) * 3;
        float ux = R[atu + 0], uy = R[atu + 1], uz = R[atu + 2];
        float vx = R[atv + 0], vy = R[atv + 1], vz = R[atv + 2];
        float ps = au + av;
        float inv = 1.0f / ps;
        float mu = au * av * inv;
        float dx = ux - vx, dy = uy - vy, dz = uz - vz;
        float r2 = dx * dx + dy * dy + dz * dz;
        float Kab = expf(-mu * r2);
        float Px = (au * ux + av * vx) * inv;
        float Py = (au * uy + av * vy) * inv;
        float Pz = (au * uz + av * vz) * inv;
        float pio = PI_F * inv;
        float Sp = pio * sqrtf(pio) * Kab;
        float Tp = mu * (3.0f - 2.0f * mu * r2) * Sp;
        float d0x = Px - R[0], d0y = Py - R[1], d0z = Pz - R[2];
        float d1x = Px - R[3], d1y = Py - R[4], d1z = Pz - R[5];
        float pc0 = d0x * d0x + d0y * d0y + d0z * d0z;
        float pc1 = d1x * d1x + d1y * d1y + d1z * d1z;
        float Vp = -(2.0f * PI_F * inv) * Kab * (f0f(ps * pc0) + f0f(ps * pc1));
        pp[lane] = ps; pK[lane] = Kab;
        pPx[lane] = Px; pPy[lane] = Py; pPz[lane] = Pz;
        pcc[lane] = cu * cv;
        pSp[lane] = Sp; pTp[lane] = Tp; pVp[lane] = Vp;
    }
    __syncthreads();

    // ---- Phase 2a: contracted S, T, V (raw, 16 lanes) ----
    if (lane < 16) {
        int i = lane >> 2, j = lane & 3;
        float aS = 0.0f, aT = 0.0f, aV = 0.0f;
        #pragma unroll
        for (int p = 0; p < 2; ++p)
        #pragma unroll
        for (int q = 0; q < 2; ++q) {
            int b = (i * 2 + p) * 8 + (j * 2 + q);
            float w = pcc[b];
            aS += w * pSp[b]; aT += w * pTp[b]; aV += w * pVp[b];
        }
        sSm[lane] = aS; sTm[lane] = aT; sVm[lane] = aV;
    }

    // ---- Phase 2b: raw ERI (all 64 lanes, 4 entries each) ----
    #pragma unroll
    for (int e0 = 0; e0 < 4; ++e0) {
        int e = lane * 4 + e0;
        int i = (e >> 6) & 3, j = (e >> 4) & 3, k = (e >> 2) & 3, l = e & 3;
        float sum = 0.0f;
        #pragma unroll
        for (int p = 0; p < 2; ++p)
        #pragma unroll
        for (int q = 0; q < 2; ++q) {
            int b1 = (i * 2 + p) * 8 + (j * 2 + q);
            float p1 = pp[b1], K1 = pK[b1], c1 = pcc[b1];
            float x1 = pPx[b1], y1 = pPy[b1], z1 = pPz[b1];
            #pragma unroll
            for (int r = 0; r < 2; ++r)
            #pragma unroll
            for (int s = 0; s < 2; ++s) {
                int b2 = (k * 2 + r) * 8 + (l * 2 + s);
                float p2 = pp[b2];
                float psum = p1 + p2;
                float dx = x1 - pPx[b2], dy = y1 - pPy[b2], dz = z1 - pPz[b2];
                float pq2 = dx * dx + dy * dy + dz * dz;
                float al = p1 * p2 / psum;
                // 2*pi^2.5 = 34.98683665
                float G = 34.98683665f / (p1 * p2 * sqrtf(psum)) * K1 * pK[b2]
                          * f0f(al * pq2);
                sum += c1 * pcc[b2] * G;
            }
        }
        sERI[e] = sum;
    }
    __syncthreads();

    // ---- Phase 3: normalization ----
    if (lane < 4) sN[lane] = rsqrtf(sSm[lane * 5]);  // diag entries i*4+i
    __syncthreads();
    if (lane < 16) {
        int i = lane >> 2, j = lane & 3;
        float nn = sN[i] * sN[j];
        sSm[lane] *= nn;
        sHc[lane] = (sTm[lane] + sVm[lane]) * nn;
    }
    #pragma unroll
    for (int e0 = 0; e0 < 4; ++e0) {
        int e = lane * 4 + e0;
        int i = (e >> 6) & 3, j = (e >> 4) & 3, k = (e >> 2) & 3, l = e & 3;
        sERI[e] *= sN[i] * sN[j] * sN[k] * sN[l];
    }
    __syncthreads();

    // ---- Phase 4: antisymmetrized Fock table Fk[ijkl] = ERI[ijkl] - 0.5*ERI[ikjl] ----
    #pragma unroll
    for (int e0 = 0; e0 < 4; ++e0) {
        int e = lane * 4 + e0;
        int i = (e >> 6) & 3, j = (e >> 4) & 3, k = (e >> 2) & 3, l = e & 3;
        sFk[e] = sERI[e] - 0.5f * sERI[((i * 4 + k) * 4 + j) * 4 + l];
    }
    __syncthreads();

    // ---- Phase 5: serial SCF on lane 0 (everything static-indexed -> registers) ----
    if (lane == 0) {
        float A[4][4], Vv[4][4], w[4];
        #pragma unroll
        for (int i = 0; i < 4; ++i)
            #pragma unroll
            for (int j = 0; j < 4; ++j) A[i][j] = sSm[i * 4 + j];
        eigh4(A, Vv, w);

        // X = S^{-1/2} = V diag(w^{-1/2}) V^T
        float X[4][4], iw[4];
        #pragma unroll
        for (int m = 0; m < 4; ++m) iw[m] = rsqrtf(w[m]);
        #pragma unroll
        for (int i = 0; i < 4; ++i)
            #pragma unroll
            for (int j = 0; j < 4; ++j) {
                float s = 0.0f;
                #pragma unroll
                for (int m = 0; m < 4; ++m) s += Vv[i][m] * iw[m] * Vv[j][m];
                X[i][j] = s;
            }

        float Hc[4][4];
        #pragma unroll
        for (int i = 0; i < 4; ++i)
            #pragma unroll
            for (int j = 0; j < 4; ++j) Hc[i][j] = sHc[i * 4 + j];

        float D[4][4];
        #pragma unroll
        for (int i = 0; i < 4; ++i)
            #pragma unroll
            for (int j = 0; j < 4; ++j) D[i][j] = 0.0f;

        float F[4][4];
        for (int it = 0; it < 30; ++it) {
            BUILD_F();
            // Fp = X^T F X
            float T1[4][4], Fp[4][4];
            #pragma unroll
            for (int i = 0; i < 4; ++i)
                #pragma unroll
                for (int j = 0; j < 4; ++j) {
                    float s = 0.0f;
                    #pragma unroll
                    for (int k = 0; k < 4; ++k) s += F[i][k] * X[k][j];
                    T1[i][j] = s;
                }
            #pragma unroll
            for (int i = 0; i < 4; ++i)
                #pragma unroll
                for (int j = 0; j < 4; ++j) {
                    float s = 0.0f;
                    #pragma unroll
                    for (int k = 0; k < 4; ++k) s += X[k][i] * T1[k][j];
                    Fp[i][j] = s;
                }
            float we[4], Ve[4][4];
            eigh4(Fp, Ve, we);
            // lowest-eigenvalue eigenvector (branchless select, static indices)
            float wmin = fminf(fminf(we[0], we[1]), fminf(we[2], we[3]));
            float cp[4];
            #pragma unroll
            for (int a = 0; a < 4; ++a)
                cp[a] = (we[0] == wmin) ? Ve[a][0]
                      : (we[1] == wmin) ? Ve[a][1]
                      : (we[2] == wmin) ? Ve[a][2] : Ve[a][3];
            // C_occ = X @ cp ; D = 2 * co co^T
            float co[4];
            #pragma unroll
            for (int a = 0; a < 4; ++a) {
                float s = 0.0f;
                #pragma unroll
                for (int b = 0; b < 4; ++b) s += X[a][b] * cp[b];
                co[a] = s;
            }
            #pragma unroll
            for (int i = 0; i < 4; ++i)
                #pragma unroll
                for (int j = 0; j < 4; ++j) D[i][j] = 2.0f * co[i] * co[j];
        }

        // final Fock + energy
        BUILD_F();
        float e = 0.0f;
        #pragma unroll
        for (int i = 0; i < 4; ++i)
            #pragma unroll
            for (int j = 0; j < 4; ++j) e += D[i][j] * (Hc[i][j] + F[i][j]);
        e *= 0.5f;
        float dx = R[0] - R[3], dy = R[1] - R[4], dz = R[2] - R[5];
        e += 1.0f / sqrtf(dx * dx + dy * dy + dz * dz);  // Z0*Z1 = 1
        out[0] = e;
    }
}

extern "C" void kernel_launch(void* const* d_in, const int* in_sizes, int n_in,
                              void* d_out, int out_size, void* d_ws, size_t ws_size,
                              hipStream_t stream) {
    const float* R = (const float*)d_in[0];
    float* out = (float*)d_out;
    hf_h2_kernel<<<1, 64, 0, stream>>>(R, out);
}

// Round 2
// 51.713 us; speedup vs baseline: 6.6869x; 6.6869x over previous
//
#include <hip/hip_runtime.h>
#include <math.h>

#define PI_F 3.14159265358979323846f

__device__ __constant__ float c_EX[8] = {5.447178f, 0.8245472f, 0.1831916f, 1.0f,
                                         5.447178f, 0.8245472f, 0.1831916f, 1.0f};
__device__ __constant__ float c_CF[8] = {0.156285f, 0.904691f, 1.0f, 0.0f,
                                         0.156285f, 0.904691f, 1.0f, 0.0f};

__device__ __forceinline__ float frcp(float x) { return __builtin_amdgcn_rcpf(x); }
__device__ __forceinline__ float frsq(float x) { return __builtin_amdgcn_rsqf(x); }

// Boys function F0 replica of reference _f0
__device__ __forceinline__ float f0f(float t) {
    float ts = fmaxf(t, 1e-12f);
    float st = sqrtf(ts);
    float big = 0.5f * sqrtf(PI_F / ts) * erff(st);
    return (t < 1e-10f) ? (1.0f - t * (1.0f / 3.0f)) : big;
}

// symmetric-pair index maps: p -> (a,b), a<=b, order
// (0,0)(0,1)(0,2)(0,3)(1,1)(1,2)(1,3)(2,2)(2,3)(3,3)
__device__ __forceinline__ void pairAB(int p, int& a, int& b) {
    a = (p < 4) ? 0 : ((p < 7) ? 1 : ((p < 9) ? 2 : 3));
    b = p - ((p < 4) ? 0 : ((p < 7) ? 3 : ((p < 9) ? 5 : 6)));
}

// One Jacobi rotation at compile-time (p,q); fast rcp for both divisions.
#define ROT(p, q) do {                                                          \
    float apq = A[p][q];                                                        \
    float diff = A[q][q] - A[p][p];                                             \
    float theta = 0.5f * diff * frcp(apq);                                      \
    float tt = copysignf(1.0f, theta) * frcp(fabsf(theta) + sqrtf(1.0f + theta * theta)); \
    tt = (apq == 0.0f) ? 0.0f : tt;                                             \
    float cr = frsq(1.0f + tt * tt);                                            \
    float sr = tt * cr;                                                         \
    _Pragma("unroll")                                                           \
    for (int k_ = 0; k_ < 4; ++k_) { float a1 = A[k_][p], a2 = A[k_][q];        \
        A[k_][p] = cr * a1 - sr * a2; A[k_][q] = sr * a1 + cr * a2; }           \
    _Pragma("unroll")                                                           \
    for (int k_ = 0; k_ < 4; ++k_) { float a1 = A[p][k_], a2 = A[q][k_];        \
        A[p][k_] = cr * a1 - sr * a2; A[q][k_] = sr * a1 + cr * a2; }           \
    _Pragma("unroll")                                                           \
    for (int k_ = 0; k_ < 4; ++k_) { float a1 = Vv[k_][p], a2 = Vv[k_][q];      \
        Vv[k_][p] = cr * a1 - sr * a2; Vv[k_][q] = sr * a1 + cr * a2; }         \
} while (0)

__device__ __forceinline__ void eigh4(float A[4][4], float Vv[4][4], float w[4]) {
    #pragma unroll
    for (int i = 0; i < 4; ++i)
        #pragma unroll
        for (int j = 0; j < 4; ++j) Vv[i][j] = (i == j) ? 1.0f : 0.0f;
    for (int sw = 0; sw < 6; ++sw) {
        ROT(0, 1); ROT(0, 2); ROT(0, 3); ROT(1, 2); ROT(1, 3); ROT(2, 3);
    }
    #pragma unroll
    for (int i = 0; i < 4; ++i) w[i] = A[i][i];
}

__global__ __launch_bounds__(64) void hf_h2_kernel(const float* __restrict__ R,
                                                   float* __restrict__ out) {
    // primitive-pair tables (64 pairs = 8 prims x 8 prims)
    __shared__ float pp[64], pK[64], pPx[64], pPy[64], pPz[64], pcc[64];
    __shared__ float pSp[64], pTp[64], pVp[64];
    __shared__ float sSm[16], sTm[16], sVm[16], sHc[16], sN[4];
    __shared__ float sERI[256], sFk[256];
    __shared__ float sX[16], sGt[256], sGG[100], sHcp[10];

    const int lane = threadIdx.x;

    // ---- Phase 1: per primitive-pair quantities ----
    {
        int u = lane >> 3, v = lane & 7;
        float au = c_EX[u], av = c_EX[v];
        float cu = c_CF[u] * powf(2.0f * au / PI_F, 0.75f);
        float cv = c_CF[v] * powf(2.0f * av / PI_F, 0.75f);
        int atu = (u >> 2) * 3, atv = (v >> 2) * 3;
        float ux = R[atu + 0], uy = R[atu + 1], uz = R[atu + 2];
        float vx = R[atv + 0], vy = R[atv + 1], vz = R[atv + 2];
        float ps = au + av;
        float inv = 1.0f / ps;
        float mu = au * av * inv;
        float dx = ux - vx, dy = uy - vy, dz = uz - vz;
        float r2 = dx * dx + dy * dy + dz * dz;
        float Kab = expf(-mu * r2);
        float Px = (au * ux + av * vx) * inv;
        float Py = (au * uy + av * vy) * inv;
        float Pz = (au * uz + av * vz) * inv;
        float pio = PI_F * inv;
        float Sp = pio * sqrtf(pio) * Kab;
        float Tp = mu * (3.0f - 2.0f * mu * r2) * Sp;
        float d0x = Px - R[0], d0y = Py - R[1], d0z = Pz - R[2];
        float d1x = Px - R[3], d1y = Py - R[4], d1z = Pz - R[5];
        float pc0 = d0x * d0x + d0y * d0y + d0z * d0z;
        float pc1 = d1x * d1x + d1y * d1y + d1z * d1z;
        float Vp = -(2.0f * PI_F * inv) * Kab * (f0f(ps * pc0) + f0f(ps * pc1));
        pp[lane] = ps; pK[lane] = Kab;
        pPx[lane] = Px; pPy[lane] = Py; pPz[lane] = Pz;
        pcc[lane] = cu * cv;
        pSp[lane] = Sp; pTp[lane] = Tp; pVp[lane] = Vp;
    }
    __syncthreads();

    // ---- Phase 2a: contracted S, T, V (raw, 16 lanes) ----
    if (lane < 16) {
        int i = lane >> 2, j = lane & 3;
        float aS = 0.0f, aT = 0.0f, aV = 0.0f;
        #pragma unroll
        for (int p = 0; p < 2; ++p)
        #pragma unroll
        for (int q = 0; q < 2; ++q) {
            int b = (i * 2 + p) * 8 + (j * 2 + q);
            float w = pcc[b];
            aS += w * pSp[b]; aT += w * pTp[b]; aV += w * pVp[b];
        }
        sSm[lane] = aS; sTm[lane] = aT; sVm[lane] = aV;
    }

    // ---- Phase 2b: raw ERI (all 64 lanes, 4 entries each) ----
    #pragma unroll
    for (int e0 = 0; e0 < 4; ++e0) {
        int e = lane * 4 + e0;
        int i = (e >> 6) & 3, j = (e >> 4) & 3, k = (e >> 2) & 3, l = e & 3;
        float sum = 0.0f;
        #pragma unroll
        for (int p = 0; p < 2; ++p)
        #pragma unroll
        for (int q = 0; q < 2; ++q) {
            int b1 = (i * 2 + p) * 8 + (j * 2 + q);
            float p1 = pp[b1], K1 = pK[b1], c1 = pcc[b1];
            float x1 = pPx[b1], y1 = pPy[b1], z1 = pPz[b1];
            #pragma unroll
            for (int r = 0; r < 2; ++r)
            #pragma unroll
            for (int s = 0; s < 2; ++s) {
                int b2 = (k * 2 + r) * 8 + (l * 2 + s);
                float p2 = pp[b2];
                float psum = p1 + p2;
                float dx = x1 - pPx[b2], dy = y1 - pPy[b2], dz = z1 - pPz[b2];
                float pq2 = dx * dx + dy * dy + dz * dz;
                float al = p1 * p2 / psum;
                float G = 34.98683665f / (p1 * p2 * sqrtf(psum)) * K1 * pK[b2]
                          * f0f(al * pq2);
                sum += c1 * pcc[b2] * G;
            }
        }
        sERI[e] = sum;
    }
    __syncthreads();

    // ---- Phase 3: normalization ----
    if (lane < 4) sN[lane] = frsq(sSm[lane * 5]);
    __syncthreads();
    if (lane < 16) {
        int i = lane >> 2, j = lane & 3;
        float nn = sN[i] * sN[j];
        sSm[lane] *= nn;
        sHc[lane] = (sTm[lane] + sVm[lane]) * nn;
    }
    #pragma unroll
    for (int e0 = 0; e0 < 4; ++e0) {
        int e = lane * 4 + e0;
        int i = (e >> 6) & 3, j = (e >> 4) & 3, k = (e >> 2) & 3, l = e & 3;
        sERI[e] *= sN[i] * sN[j] * sN[k] * sN[l];
    }
    __syncthreads();

    // ---- Phase 4: antisymmetrized table Fk[ijkl] = ERI[ijkl] - 0.5*ERI[ikjl] ----
    #pragma unroll
    for (int e0 = 0; e0 < 4; ++e0) {
        int e = lane * 4 + e0;
        int i = (e >> 6) & 3, j = (e >> 4) & 3, k = (e >> 2) & 3, l = e & 3;
        sFk[e] = sERI[e] - 0.5f * sERI[((i * 4 + k) * 4 + j) * 4 + l];
    }
    __syncthreads();

    // ---- Phase 5: lane 0 -- one-time eigh(S), X = S^{-1/2}, write X to LDS ----
    if (lane == 0) {
        float A[4][4], Vv[4][4], w4[4];
        #pragma unroll
        for (int i = 0; i < 4; ++i)
            #pragma unroll
            for (int j = 0; j < 4; ++j) A[i][j] = sSm[i * 4 + j];
        eigh4(A, Vv, w4);
        float iw[4];
        #pragma unroll
        for (int m = 0; m < 4; ++m) iw[m] = frsq(w4[m]);
        #pragma unroll
        for (int i = 0; i < 4; ++i)
            #pragma unroll
            for (int j = 0; j < 4; ++j) {
                float s = 0.0f;
                #pragma unroll
                for (int m = 0; m < 4; ++m) s += Vv[i][m] * iw[m] * Vv[j][m];
                sX[i * 4 + j] = s;
            }
    }
    __syncthreads();

    // ---- Phase 6a: Gt[a][b][k][l] = sum_ij X_ia X_jb Fk[ijkl]  (64 lanes x 4) ----
    {
        int t0 = lane * 4;
        int a = (t0 >> 6) & 3, b = (t0 >> 4) & 3;
        float xx[4][4];
        #pragma unroll
        for (int i = 0; i < 4; ++i)
            #pragma unroll
            for (int j = 0; j < 4; ++j) xx[i][j] = sX[i * 4 + a] * sX[j * 4 + b];
        #pragma unroll
        for (int l = 0; l < 4; ++l) {
            float s = 0.0f;
            #pragma unroll
            for (int i = 0; i < 4; ++i)
                #pragma unroll
                for (int j = 0; j < 4; ++j)
                    s += xx[i][j] * sFk[(i * 4 + j) * 16 + (t0 & 15) + l];
            sGt[t0 + l] = s;
        }
    }
    __syncthreads();

    // ---- Phase 6b: GG[p][q] (100 coeffs) + Hcp[10], fully transformed basis ----
    if (lane < 50) {
        #pragma unroll
        for (int e0 = 0; e0 < 2; ++e0) {
            int g = lane * 2 + e0;
            int p = g / 10, q = g - p * 10;
            int a, b, c, d;
            pairAB(p, a, b);
            pairAB(q, c, d);
            float s = 0.0f;
            #pragma unroll
            for (int k = 0; k < 4; ++k)
                #pragma unroll
                for (int l = 0; l < 4; ++l) {
                    float W = sX[k * 4 + c] * sX[l * 4 + d];
                    if (c != d) W += sX[k * 4 + d] * sX[l * 4 + c];
                    s += W * sGt[((a * 4 + b) * 4 + k) * 4 + l];
                }
            sGG[g] = 2.0f * s;
        }
    } else if (lane < 60) {
        int p = lane - 50;
        int a, b;
        pairAB(p, a, b);
        float s = 0.0f;
        #pragma unroll
        for (int i = 0; i < 4; ++i)
            #pragma unroll
            for (int j = 0; j < 4; ++j)
                s += sX[i * 4 + a] * sHc[i * 4 + j] * sX[j * 4 + b];
        sHcp[p] = s;
    }
    __syncthreads();

    // ---- Phase 7: lane 0 -- register-only SCF via shifted power iteration ----
    if (lane == 0) {
        float GGr[100], Hr[10], Mp[10];
        #pragma unroll
        for (int g = 0; g < 100; ++g) GGr[g] = sGG[g];
        #pragma unroll
        for (int p = 0; p < 10; ++p) Hr[p] = sHcp[p];

        float v0, v1, v2, v3;

        auto buildM = [&]() {
            float w[10] = {v0 * v0, v0 * v1, v0 * v2, v0 * v3, v1 * v1,
                           v1 * v2, v1 * v3, v2 * v2, v2 * v3, v3 * v3};
            #pragma unroll
            for (int p = 0; p < 10; ++p) {
                float s = Hr[p];
                #pragma unroll
                for (int q = 0; q < 10; ++q) s = fmaf(GGr[p * 10 + q], w[q], s);
                Mp[p] = s;
            }
        };
        auto gersh = [&]() {
            float r0 = Mp[0] + fabsf(Mp[1]) + fabsf(Mp[2]) + fabsf(Mp[3]);
            float r1 = Mp[4] + fabsf(Mp[1]) + fabsf(Mp[5]) + fabsf(Mp[6]);
            float r2 = Mp[7] + fabsf(Mp[2]) + fabsf(Mp[5]) + fabsf(Mp[8]);
            float r3 = Mp[9] + fabsf(Mp[3]) + fabsf(Mp[6]) + fabsf(Mp[8]);
            return fmaxf(fmaxf(r0, r1), fmaxf(r2, r3));
        };
        auto pstep = [&](float sig) {
            float m0 = fmaf(Mp[0], v0, fmaf(Mp[1], v1, fmaf(Mp[2], v2, Mp[3] * v3)));
            float m1 = fmaf(Mp[1], v0, fmaf(Mp[4], v1, fmaf(Mp[5], v2, Mp[6] * v3)));
            float m2 = fmaf(Mp[2], v0, fmaf(Mp[5], v1, fmaf(Mp[7], v2, Mp[8] * v3)));
            float m3 = fmaf(Mp[3], v0, fmaf(Mp[6], v1, fmaf(Mp[8], v2, Mp[9] * v3)));
            v0 = fmaf(sig, v0, -m0);
            v1 = fmaf(sig, v1, -m1);
            v2 = fmaf(sig, v2, -m2);
            v3 = fmaf(sig, v3, -m3);
        };
        auto vnorm = [&]() {
            float nn = v0 * v0 + v1 * v1 + v2 * v2 + v3 * v3;
            float r = frsq(nn);
            v0 *= r; v1 *= r; v2 *= r; v3 *= r;
        };

        // SCF step 1: D=0 -> Fp = Hcp. Bootstrap eigenvector by 16 normalized
        // shifted power iterations from a diag-min-biased start.
        #pragma unroll
        for (int p = 0; p < 10; ++p) Mp[p] = Hr[p];
        {
            float dmin = fminf(fminf(Mp[0], Mp[4]), fminf(Mp[7], Mp[9]));
            v0 = (Mp[0] == dmin) ? 1.0f : 0.25f;
            v1 = (Mp[4] == dmin) ? 1.0f : 0.25f;
            v2 = (Mp[7] == dmin) ? 1.0f : 0.25f;
            v3 = (Mp[9] == dmin) ? 1.0f : 0.25f;
            float sig = gersh();
            for (int t = 0; t < 16; ++t) { pstep(sig); vnorm(); }
        }

        // SCF steps 2..30: warm-started, 4 power iterations each.
        for (int it = 1; it < 30; ++it) {
            buildM();
            float sig = gersh();
            pstep(sig); pstep(sig); pstep(sig); pstep(sig);
            vnorm();
        }

        // Final Fock from converged v; energy fully in transformed basis:
        // e_elec = v^T (Hcp + Fp) v
        buildM();
        float A0 = Hr[0] + Mp[0], A1 = Hr[1] + Mp[1], A2 = Hr[2] + Mp[2];
        float A3 = Hr[3] + Mp[3], A4 = Hr[4] + Mp[4], A5 = Hr[5] + Mp[5];
        float A6 = Hr[6] + Mp[6], A7 = Hr[7] + Mp[7], A8 = Hr[8] + Mp[8];
        float A9 = Hr[9] + Mp[9];
        float e = A0 * v0 * v0 + A4 * v1 * v1 + A7 * v2 * v2 + A9 * v3 * v3
                + 2.0f * (A1 * v0 * v1 + A2 * v0 * v2 + A3 * v0 * v3
                        + A5 * v1 * v2 + A6 * v1 * v3 + A8 * v2 * v3);
        float dx = R[0] - R[3], dy = R[1] - R[4], dz = R[2] - R[5];
        e += frsq(dx * dx + dy * dy + dz * dz);  // Z0*Z1 = 1
        out[0] = e;
    }
}

extern "C" void kernel_launch(void* const* d_in, const int* in_sizes, int n_in,
                              void* d_out, int out_size, void* d_ws, size_t ws_size,
                              hipStream_t stream) {
    const float* R = (const float*)d_in[0];
    float* out = (float*)d_out;
    hf_h2_kernel<<<1, 64, 0, stream>>>(R, out);
}

// Round 3
// 34.787 us; speedup vs baseline: 9.9406x; 1.4866x over previous
//
#include <hip/hip_runtime.h>
#include <math.h>

#define PI_F 3.14159265358979323846f

__device__ __constant__ float c_EX[8] = {5.447178f, 0.8245472f, 0.1831916f, 1.0f,
                                         5.447178f, 0.8245472f, 0.1831916f, 1.0f};
__device__ __constant__ float c_CF[8] = {0.156285f, 0.904691f, 1.0f, 0.0f,
                                         0.156285f, 0.904691f, 1.0f, 0.0f};

__device__ __forceinline__ float frcp(float x) { return __builtin_amdgcn_rcpf(x); }
__device__ __forceinline__ float frsq(float x) { return __builtin_amdgcn_rsqf(x); }

// Boys F0, matching reference _f0: 0.5*sqrt(pi/t)*erf(sqrt(t)), series for tiny t.
// 0.5*sqrt(pi) = 0.88622692545
__device__ __forceinline__ float f0f(float t) {
    float ts = fmaxf(t, 1e-12f);
    float st = sqrtf(ts);
    float big = 0.88622692545f * frsq(ts) * erff(st);
    return (t < 1e-10f) ? (1.0f - t * (1.0f / 3.0f)) : big;
}

// symmetric-pair index maps: p -> (a,b), a<=b, order
// (0,0)(0,1)(0,2)(0,3)(1,1)(1,2)(1,3)(2,2)(2,3)(3,3)
__device__ __forceinline__ void pairAB(int p, int& a, int& b) {
    a = (p < 4) ? 0 : ((p < 7) ? 1 : ((p < 9) ? 2 : 3));
    b = p - ((p < 4) ? 0 : ((p < 7) ? 3 : ((p < 9) ? 5 : 6)));
}

// One Jacobi rotation at compile-time (p,q); fast rcp for both divisions.
#define ROT(p, q) do {                                                          \
    float apq = A[p][q];                                                        \
    float diff = A[q][q] - A[p][p];                                             \
    float theta = 0.5f * diff * frcp(apq);                                      \
    float tt = copysignf(1.0f, theta) * frcp(fabsf(theta) + sqrtf(1.0f + theta * theta)); \
    tt = (apq == 0.0f) ? 0.0f : tt;                                             \
    float cr = frsq(1.0f + tt * tt);                                            \
    float sr = tt * cr;                                                         \
    _Pragma("unroll")                                                           \
    for (int k_ = 0; k_ < 4; ++k_) { float a1 = A[k_][p], a2 = A[k_][q];        \
        A[k_][p] = cr * a1 - sr * a2; A[k_][q] = sr * a1 + cr * a2; }           \
    _Pragma("unroll")                                                           \
    for (int k_ = 0; k_ < 4; ++k_) { float a1 = A[p][k_], a2 = A[q][k_];        \
        A[p][k_] = cr * a1 - sr * a2; A[q][k_] = sr * a1 + cr * a2; }           \
    _Pragma("unroll")                                                           \
    for (int k_ = 0; k_ < 4; ++k_) { float a1 = Vv[k_][p], a2 = Vv[k_][q];      \
        Vv[k_][p] = cr * a1 - sr * a2; Vv[k_][q] = sr * a1 + cr * a2; }         \
} while (0)

__device__ __forceinline__ void eigh4(float A[4][4], float Vv[4][4], float w[4]) {
    #pragma unroll
    for (int i = 0; i < 4; ++i)
        #pragma unroll
        for (int j = 0; j < 4; ++j) Vv[i][j] = (i == j) ? 1.0f : 0.0f;
    for (int sw = 0; sw < 6; ++sw) {
        ROT(0, 1); ROT(0, 2); ROT(0, 3); ROT(1, 2); ROT(1, 3); ROT(2, 3);
    }
    #pragma unroll
    for (int i = 0; i < 4; ++i) w[i] = A[i][i];
}

__global__ __launch_bounds__(64, 1) void hf_h2_kernel(const float* __restrict__ R,
                                                      float* __restrict__ out) {
    // primitive-pair tables (64 pairs = 8 prims x 8 prims)
    __shared__ float pp[64], pK[64], pPx[64], pPy[64], pPz[64], pcc[64];
    __shared__ float pSp[64], pTp[64], pVp[64];
    __shared__ float sSm[16], sTm[16], sVm[16], sHc[16], sN[4];
    __shared__ float sERI[256], sFk[256];
    __shared__ float sX[16], sGt[256], sGG[100], sHcp[10];

    const int lane = threadIdx.x;

    // ---- Phase 1: per primitive-pair quantities ----
    {
        int u = lane >> 3, v = lane & 7;
        float au = c_EX[u], av = c_EX[v];
        float cu = c_CF[u] * powf(2.0f * au / PI_F, 0.75f);
        float cv = c_CF[v] * powf(2.0f * av / PI_F, 0.75f);
        int atu = (u >> 2) * 3, atv = (v >> 2) * 3;
        float ux = R[atu + 0], uy = R[atu + 1], uz = R[atu + 2];
        float vx = R[atv + 0], vy = R[atv + 1], vz = R[atv + 2];
        float ps = au + av;
        float inv = frcp(ps);
        float mu = au * av * inv;
        float dx = ux - vx, dy = uy - vy, dz = uz - vz;
        float r2 = dx * dx + dy * dy + dz * dz;
        float Kab = expf(-mu * r2);
        float Px = (au * ux + av * vx) * inv;
        float Py = (au * uy + av * vy) * inv;
        float Pz = (au * uz + av * vz) * inv;
        float pio = PI_F * inv;
        float Sp = pio * sqrtf(pio) * Kab;
        float Tp = mu * (3.0f - 2.0f * mu * r2) * Sp;
        float d0x = Px - R[0], d0y = Py - R[1], d0z = Pz - R[2];
        float d1x = Px - R[3], d1y = Py - R[4], d1z = Pz - R[5];
        float pc0 = d0x * d0x + d0y * d0y + d0z * d0z;
        float pc1 = d1x * d1x + d1y * d1y + d1z * d1z;
        float Vp = -(2.0f * PI_F * inv) * Kab * (f0f(ps * pc0) + f0f(ps * pc1));
        pp[lane] = ps; pK[lane] = Kab;
        pPx[lane] = Px; pPy[lane] = Py; pPz[lane] = Pz;
        pcc[lane] = cu * cv;
        pSp[lane] = Sp; pTp[lane] = Tp; pVp[lane] = Vp;
    }
    __syncthreads();

    // ---- Phase 2a: contracted S, T, V (raw, 16 lanes) ----
    if (lane < 16) {
        int i = lane >> 2, j = lane & 3;
        float aS = 0.0f, aT = 0.0f, aV = 0.0f;
        #pragma unroll
        for (int p = 0; p < 2; ++p)
        #pragma unroll
        for (int q = 0; q < 2; ++q) {
            int b = (i * 2 + p) * 8 + (j * 2 + q);
            float w = pcc[b];
            aS += w * pSp[b]; aT += w * pTp[b]; aV += w * pVp[b];
        }
        sSm[lane] = aS; sTm[lane] = aT; sVm[lane] = aV;
    }

    // ---- Phase 2b: unique raw ERI entries (55 lanes, 1 entry x 16 quads each) ----
    // unique over pair-of-pairs (P<=Q), P,Q in [0,10) symmetric orbital pairs
    float uval = 0.0f;
    int ui, uj, uk, ul;
    {
        int t = (lane < 55) ? lane : 0;
        int P = (t >= 10) + (t >= 19) + (t >= 27) + (t >= 34) + (t >= 40)
              + (t >= 45) + (t >= 49) + (t >= 52) + (t >= 54);
        int base = P * 10 - ((P * (P - 1)) >> 1);
        int Q = t - base + P;
        pairAB(P, ui, uj);
        pairAB(Q, uk, ul);
        float sum = 0.0f;
        #pragma unroll
        for (int p = 0; p < 2; ++p)
        #pragma unroll
        for (int q = 0; q < 2; ++q) {
            int b1 = (ui * 2 + p) * 8 + (uj * 2 + q);
            float p1 = pp[b1], K1 = pK[b1], c1 = pcc[b1];
            float x1 = pPx[b1], y1 = pPy[b1], z1 = pPz[b1];
            #pragma unroll
            for (int r = 0; r < 2; ++r)
            #pragma unroll
            for (int s = 0; s < 2; ++s) {
                int b2 = (uk * 2 + r) * 8 + (ul * 2 + s);
                float p2 = pp[b2];
                float psum = p1 + p2;
                float dx = x1 - pPx[b2], dy = y1 - pPy[b2], dz = z1 - pPz[b2];
                float pq2 = dx * dx + dy * dy + dz * dz;
                float al = p1 * p2 * frcp(psum);
                // 2*pi^2.5 = 34.98683665
                float G = 34.98683665f * frcp(p1 * p2 * sqrtf(psum)) * K1 * pK[b2]
                          * f0f(al * pq2);
                sum += c1 * pcc[b2] * G;
            }
        }
        uval = sum;
    }
    __syncthreads();

    // ---- Phase 3: normalization factors ----
    if (lane < 4) sN[lane] = frsq(sSm[lane * 5]);
    __syncthreads();
    if (lane < 16) {
        int i = lane >> 2, j = lane & 3;
        float nn = sN[i] * sN[j];
        sSm[lane] *= nn;
        sHc[lane] = (sTm[lane] + sVm[lane]) * nn;
    }
    // scale unique ERI + scatter to all 8 symmetric positions
    if (lane < 55) {
        float v = uval * sN[ui] * sN[uj] * sN[uk] * sN[ul];
        int i = ui, j = uj, k = uk, l = ul;
        sERI[((i * 4 + j) * 4 + k) * 4 + l] = v;
        sERI[((j * 4 + i) * 4 + k) * 4 + l] = v;
        sERI[((i * 4 + j) * 4 + l) * 4 + k] = v;
        sERI[((j * 4 + i) * 4 + l) * 4 + k] = v;
        sERI[((k * 4 + l) * 4 + i) * 4 + j] = v;
        sERI[((l * 4 + k) * 4 + i) * 4 + j] = v;
        sERI[((k * 4 + l) * 4 + j) * 4 + i] = v;
        sERI[((l * 4 + k) * 4 + j) * 4 + i] = v;
    }
    __syncthreads();

    // ---- Phase 4: antisymmetrized table Fk[ijkl] = ERI[ijkl] - 0.5*ERI[ikjl] ----
    #pragma unroll
    for (int e0 = 0; e0 < 4; ++e0) {
        int e = lane * 4 + e0;
        int i = (e >> 6) & 3, j = (e >> 4) & 3, k = (e >> 2) & 3, l = e & 3;
        sFk[e] = sERI[e] - 0.5f * sERI[((i * 4 + k) * 4 + j) * 4 + l];
    }
    __syncthreads();

    // ---- Phase 5: lane 0 -- one-time eigh(S), X = S^{-1/2}, write X to LDS ----
    if (lane == 0) {
        float A[4][4], Vv[4][4], w4[4];
        #pragma unroll
        for (int i = 0; i < 4; ++i)
            #pragma unroll
            for (int j = 0; j < 4; ++j) A[i][j] = sSm[i * 4 + j];
        eigh4(A, Vv, w4);
        float iw[4];
        #pragma unroll
        for (int m = 0; m < 4; ++m) iw[m] = frsq(w4[m]);
        #pragma unroll
        for (int i = 0; i < 4; ++i)
            #pragma unroll
            for (int j = 0; j < 4; ++j) {
                float s = 0.0f;
                #pragma unroll
                for (int m = 0; m < 4; ++m) s += Vv[i][m] * iw[m] * Vv[j][m];
                sX[i * 4 + j] = s;
            }
    }
    __syncthreads();

    // ---- Phase 6a: Gt[a][b][k][l] = sum_ij X_ia X_jb Fk[ijkl]  (64 lanes x 4) ----
    {
        int t0 = lane * 4;
        int a = (t0 >> 6) & 3, b = (t0 >> 4) & 3;
        float xx[4][4];
        #pragma unroll
        for (int i = 0; i < 4; ++i)
            #pragma unroll
            for (int j = 0; j < 4; ++j) xx[i][j] = sX[i * 4 + a] * sX[j * 4 + b];
        #pragma unroll
        for (int l = 0; l < 4; ++l) {
            float s = 0.0f;
            #pragma unroll
            for (int i = 0; i < 4; ++i)
                #pragma unroll
                for (int j = 0; j < 4; ++j)
                    s += xx[i][j] * sFk[(i * 4 + j) * 16 + (t0 & 15) + l];
            sGt[t0 + l] = s;
        }
    }
    __syncthreads();

    // ---- Phase 6b: GG[p][q] (100 coeffs) + Hcp[10], fully transformed basis ----
    if (lane < 50) {
        #pragma unroll
        for (int e0 = 0; e0 < 2; ++e0) {
            int g = lane * 2 + e0;
            int p = g / 10, q = g - p * 10;
            int a, b, c, d;
            pairAB(p, a, b);
            pairAB(q, c, d);
            float s = 0.0f;
            #pragma unroll
            for (int k = 0; k < 4; ++k)
                #pragma unroll
                for (int l = 0; l < 4; ++l) {
                    float W = sX[k * 4 + c] * sX[l * 4 + d];
                    if (c != d) W += sX[k * 4 + d] * sX[l * 4 + c];
                    s += W * sGt[((a * 4 + b) * 4 + k) * 4 + l];
                }
            sGG[g] = 2.0f * s;
        }
    } else if (lane < 60) {
        int p = lane - 50;
        int a, b;
        pairAB(p, a, b);
        float s = 0.0f;
        #pragma unroll
        for (int i = 0; i < 4; ++i)
            #pragma unroll
            for (int j = 0; j < 4; ++j)
                s += sX[i * 4 + a] * sHc[i * 4 + j] * sX[j * 4 + b];
        sHcp[p] = s;
    }
    __syncthreads();

    // ---- Phase 7: lane 0 -- register-only SCF via shifted power iteration ----
    if (lane == 0) {
        float GGr[100], Hr[10], Mp[10];
        #pragma unroll
        for (int g = 0; g < 100; ++g) GGr[g] = sGG[g];
        #pragma unroll
        for (int p = 0; p < 10; ++p) Hr[p] = sHcp[p];

        float v0, v1, v2, v3;

        auto buildM = [&]() {
            float w[10] = {v0 * v0, v0 * v1, v0 * v2, v0 * v3, v1 * v1,
                           v1 * v2, v1 * v3, v2 * v2, v2 * v3, v3 * v3};
            #pragma unroll
            for (int p = 0; p < 10; ++p) {
                float s = Hr[p];
                #pragma unroll
                for (int q = 0; q < 10; ++q) s = fmaf(GGr[p * 10 + q], w[q], s);
                Mp[p] = s;
            }
        };
        auto gersh = [&]() {
            float r0 = Mp[0] + fabsf(Mp[1]) + fabsf(Mp[2]) + fabsf(Mp[3]);
            float r1 = Mp[4] + fabsf(Mp[1]) + fabsf(Mp[5]) + fabsf(Mp[6]);
            float r2 = Mp[7] + fabsf(Mp[2]) + fabsf(Mp[5]) + fabsf(Mp[8]);
            float r3 = Mp[9] + fabsf(Mp[3]) + fabsf(Mp[6]) + fabsf(Mp[8]);
            return fmaxf(fmaxf(r0, r1), fmaxf(r2, r3));
        };
        auto pstep = [&](float sig) {
            float m0 = fmaf(Mp[0], v0, fmaf(Mp[1], v1, fmaf(Mp[2], v2, Mp[3] * v3)));
            float m1 = fmaf(Mp[1], v0, fmaf(Mp[4], v1, fmaf(Mp[5], v2, Mp[6] * v3)));
            float m2 = fmaf(Mp[2], v0, fmaf(Mp[5], v1, fmaf(Mp[7], v2, Mp[8] * v3)));
            float m3 = fmaf(Mp[3], v0, fmaf(Mp[6], v1, fmaf(Mp[8], v2, Mp[9] * v3)));
            v0 = fmaf(sig, v0, -m0);
            v1 = fmaf(sig, v1, -m1);
            v2 = fmaf(sig, v2, -m2);
            v3 = fmaf(sig, v3, -m3);
        };
        auto vnorm = [&]() {
            float nn = v0 * v0 + v1 * v1 + v2 * v2 + v3 * v3;
            float r = frsq(nn);
            v0 *= r; v1 *= r; v2 *= r; v3 *= r;
        };

        // SCF step 1: D=0 -> Fp = Hcp. Bootstrap eigenvector by 16 normalized
        // shifted power iterations from a diag-min-biased start.
        #pragma unroll
        for (int p = 0; p < 10; ++p) Mp[p] = Hr[p];
        {
            float dmin = fminf(fminf(Mp[0], Mp[4]), fminf(Mp[7], Mp[9]));
            v0 = (Mp[0] == dmin) ? 1.0f : 0.25f;
            v1 = (Mp[4] == dmin) ? 1.0f : 0.25f;
            v2 = (Mp[7] == dmin) ? 1.0f : 0.25f;
            v3 = (Mp[9] == dmin) ? 1.0f : 0.25f;
            float sig = gersh();
            for (int t = 0; t < 16; ++t) { pstep(sig); vnorm(); }
        }

        // SCF steps 2..30: warm-started, 4 power iterations each.
        for (int it = 1; it < 30; ++it) {
            buildM();
            float sig = gersh();
            pstep(sig); pstep(sig); pstep(sig); pstep(sig);
            vnorm();
        }

        // Final Fock from converged v; energy fully in transformed basis:
        // e_elec = v^T (Hcp + Fp) v
        buildM();
        float A0 = Hr[0] + Mp[0], A1 = Hr[1] + Mp[1], A2 = Hr[2] + Mp[2];
        float A3 = Hr[3] + Mp[3], A4 = Hr[4] + Mp[4], A5 = Hr[5] + Mp[5];
        float A6 = Hr[6] + Mp[6], A7 = Hr[7] + Mp[7], A8 = Hr[8] + Mp[8];
        float A9 = Hr[9] + Mp[9];
        float e = A0 * v0 * v0 + A4 * v1 * v1 + A7 * v2 * v2 + A9 * v3 * v3
                + 2.0f * (A1 * v0 * v1 + A2 * v0 * v2 + A3 * v0 * v3
                        + A5 * v1 * v2 + A6 * v1 * v3 + A8 * v2 * v3);
        float dx = R[0] - R[3], dy = R[1] - R[4], dz = R[2] - R[5];
        e += frsq(dx * dx + dy * dy + dz * dz);  // Z0*Z1 = 1
        out[0] = e;
    }
}

extern "C" void kernel_launch(void* const* d_in, const int* in_sizes, int n_in,
                              void* d_out, int out_size, void* d_ws, size_t ws_size,
                              hipStream_t stream) {
    const float* R = (const float*)d_in[0];
    float* out = (float*)d_out;
    hf_h2_kernel<<<1, 64, 0, stream>>>(R, out);
}

// Round 4
// 20.305 us; speedup vs baseline: 17.0302x; 1.7132x over previous
//
#include <hip/hip_runtime.h>
#include <math.h>

#define PI_F 3.14159265358979323846f

__device__ __constant__ float c_EX[8] = {5.447178f, 0.8245472f, 0.1831916f, 1.0f,
                                         5.447178f, 0.8245472f, 0.1831916f, 1.0f};
// c_CF * (2*EX/pi)^0.75 precomputed in double precision (powf inputs are constants)
__device__ __constant__ float c_NC[8] = {0.39715137f, 0.55792070f, 0.19956670f, 0.0f,
                                         0.39715137f, 0.55792070f, 0.19956670f, 0.0f};

__device__ __forceinline__ float frcp(float x) { return __builtin_amdgcn_rcpf(x); }
__device__ __forceinline__ float frsq(float x) { return __builtin_amdgcn_rsqf(x); }

// Boys F0, matching reference _f0
__device__ __forceinline__ float f0f(float t) {
    float ts = fmaxf(t, 1e-12f);
    float st = sqrtf(ts);
    float big = 0.88622692545f * frsq(ts) * erff(st);
    return (t < 1e-10f) ? (1.0f - t * (1.0f / 3.0f)) : big;
}

// symmetric-pair index maps: p -> (a,b), a<=b, order
// (0,0)(0,1)(0,2)(0,3)(1,1)(1,2)(1,3)(2,2)(2,3)(3,3)
__device__ __forceinline__ void pairAB(int p, int& a, int& b) {
    a = (p < 4) ? 0 : ((p < 7) ? 1 : ((p < 9) ? 2 : 3));
    b = p - ((p < 4) ? 0 : ((p < 7) ? 3 : ((p < 9) ? 5 : 6)));
}

// One Jacobi rotation at compile-time (p,q); fast rcp for both divisions.
#define ROT(p, q) do {                                                          \
    float apq = A[p][q];                                                        \
    float diff = A[q][q] - A[p][p];                                             \
    float theta = 0.5f * diff * frcp(apq);                                      \
    float tt = copysignf(1.0f, theta) * frcp(fabsf(theta) + sqrtf(1.0f + theta * theta)); \
    tt = (apq == 0.0f) ? 0.0f : tt;                                             \
    float cr = frsq(1.0f + tt * tt);                                            \
    float sr = tt * cr;                                                         \
    _Pragma("unroll")                                                           \
    for (int k_ = 0; k_ < 4; ++k_) { float a1 = A[k_][p], a2 = A[k_][q];        \
        A[k_][p] = cr * a1 - sr * a2; A[k_][q] = sr * a1 + cr * a2; }           \
    _Pragma("unroll")                                                           \
    for (int k_ = 0; k_ < 4; ++k_) { float a1 = A[p][k_], a2 = A[q][k_];        \
        A[p][k_] = cr * a1 - sr * a2; A[q][k_] = sr * a1 + cr * a2; }           \
    _Pragma("unroll")                                                           \
    for (int k_ = 0; k_ < 4; ++k_) { float a1 = Vv[k_][p], a2 = Vv[k_][q];      \
        Vv[k_][p] = cr * a1 - sr * a2; Vv[k_][q] = sr * a1 + cr * a2; }         \
} while (0)

__device__ __forceinline__ void eigh4(float A[4][4], float Vv[4][4], float w[4]) {
    #pragma unroll
    for (int i = 0; i < 4; ++i)
        #pragma unroll
        for (int j = 0; j < 4; ++j) Vv[i][j] = (i == j) ? 1.0f : 0.0f;
    for (int sw = 0; sw < 4; ++sw) {   // 4 sweeps: off-diag ~1e-10, X-error 2nd order in e
        ROT(0, 1); ROT(0, 2); ROT(0, 3); ROT(1, 2); ROT(1, 3); ROT(2, 3);
    }
    #pragma unroll
    for (int i = 0; i < 4; ++i) w[i] = A[i][i];
}

__global__ __launch_bounds__(64, 1) void hf_h2_kernel(const float* __restrict__ R,
                                                      float* __restrict__ out) {
    __shared__ float pp[64], pK[64], pPx[64], pPy[64], pPz[64], pcc[64];
    __shared__ float pSp[64], pTp[64], pVp[64];
    __shared__ float sSm[16], sTm[16], sVm[16], sHc[16], sN[4];
    __shared__ float sERI[256], sFk[256];
    __shared__ float sX[16], sGt[256], sGG[100], sHcp[10];

    const int lane = threadIdx.x;

    // ---- Phase 1: per primitive-pair quantities ----
    {
        int u = lane >> 3, v = lane & 7;
        float au = c_EX[u], av = c_EX[v];
        float cu = c_NC[u], cv = c_NC[v];
        int atu = (u >> 2) * 3, atv = (v >> 2) * 3;
        float ux = R[atu + 0], uy = R[atu + 1], uz = R[atu + 2];
        float vx = R[atv + 0], vy = R[atv + 1], vz = R[atv + 2];
        float ps = au + av;
        float inv = frcp(ps);
        float mu = au * av * inv;
        float dx = ux - vx, dy = uy - vy, dz = uz - vz;
        float r2 = dx * dx + dy * dy + dz * dz;
        float Kab = expf(-mu * r2);
        float Px = (au * ux + av * vx) * inv;
        float Py = (au * uy + av * vy) * inv;
        float Pz = (au * uz + av * vz) * inv;
        float pio = PI_F * inv;
        float Sp = pio * sqrtf(pio) * Kab;
        float Tp = mu * (3.0f - 2.0f * mu * r2) * Sp;
        float d0x = Px - R[0], d0y = Py - R[1], d0z = Pz - R[2];
        float d1x = Px - R[3], d1y = Py - R[4], d1z = Pz - R[5];
        float pc0 = d0x * d0x + d0y * d0y + d0z * d0z;
        float pc1 = d1x * d1x + d1y * d1y + d1z * d1z;
        float Vp = -(2.0f * PI_F * inv) * Kab * (f0f(ps * pc0) + f0f(ps * pc1));
        pp[lane] = ps; pK[lane] = Kab;
        pPx[lane] = Px; pPy[lane] = Py; pPz[lane] = Pz;
        pcc[lane] = cu * cv;
        pSp[lane] = Sp; pTp[lane] = Tp; pVp[lane] = Vp;
    }
    __syncthreads();

    // ---- Phase 2a: contracted S, T, V (raw, 16 lanes) ----
    if (lane < 16) {
        int i = lane >> 2, j = lane & 3;
        float aS = 0.0f, aT = 0.0f, aV = 0.0f;
        #pragma unroll
        for (int p = 0; p < 2; ++p)
        #pragma unroll
        for (int q = 0; q < 2; ++q) {
            int b = (i * 2 + p) * 8 + (j * 2 + q);
            float w = pcc[b];
            aS += w * pSp[b]; aT += w * pTp[b]; aV += w * pVp[b];
        }
        sSm[lane] = aS; sTm[lane] = aT; sVm[lane] = aV;
    }

    // ---- Phase 2b: unique raw ERI entries (55 lanes, 1 entry x 16 quads each) ----
    float uval = 0.0f;
    int ui, uj, uk, ul;
    {
        int t = (lane < 55) ? lane : 0;
        int P = (t >= 10) + (t >= 19) + (t >= 27) + (t >= 34) + (t >= 40)
              + (t >= 45) + (t >= 49) + (t >= 52) + (t >= 54);
        int base = P * 10 - ((P * (P - 1)) >> 1);
        int Q = t - base + P;
        pairAB(P, ui, uj);
        pairAB(Q, uk, ul);
        float sum = 0.0f;
        #pragma unroll
        for (int p = 0; p < 2; ++p)
        #pragma unroll
        for (int q = 0; q < 2; ++q) {
            int b1 = (ui * 2 + p) * 8 + (uj * 2 + q);
            float p1 = pp[b1], K1 = pK[b1], c1 = pcc[b1];
            float x1 = pPx[b1], y1 = pPy[b1], z1 = pPz[b1];
            #pragma unroll
            for (int r = 0; r < 2; ++r)
            #pragma unroll
            for (int s = 0; s < 2; ++s) {
                int b2 = (uk * 2 + r) * 8 + (ul * 2 + s);
                float p2 = pp[b2];
                float psum = p1 + p2;
                float dx = x1 - pPx[b2], dy = y1 - pPy[b2], dz = z1 - pPz[b2];
                float pq2 = dx * dx + dy * dy + dz * dz;
                float al = p1 * p2 * frcp(psum);
                float G = 34.98683665f * frcp(p1 * p2 * sqrtf(psum)) * K1 * pK[b2]
                          * f0f(al * pq2);   // 2*pi^2.5 = 34.98683665
                sum += c1 * pcc[b2] * G;
            }
        }
        uval = sum;
    }
    __syncthreads();

    // ---- Phase 3: normalization factors ----
    if (lane < 4) sN[lane] = frsq(sSm[lane * 5]);
    __syncthreads();
    if (lane < 16) {
        int i = lane >> 2, j = lane & 3;
        float nn = sN[i] * sN[j];
        sSm[lane] *= nn;
        sHc[lane] = (sTm[lane] + sVm[lane]) * nn;
    }
    if (lane < 55) {
        float v = uval * sN[ui] * sN[uj] * sN[uk] * sN[ul];
        int i = ui, j = uj, k = uk, l = ul;
        sERI[((i * 4 + j) * 4 + k) * 4 + l] = v;
        sERI[((j * 4 + i) * 4 + k) * 4 + l] = v;
        sERI[((i * 4 + j) * 4 + l) * 4 + k] = v;
        sERI[((j * 4 + i) * 4 + l) * 4 + k] = v;
        sERI[((k * 4 + l) * 4 + i) * 4 + j] = v;
        sERI[((l * 4 + k) * 4 + i) * 4 + j] = v;
        sERI[((k * 4 + l) * 4 + j) * 4 + i] = v;
        sERI[((l * 4 + k) * 4 + j) * 4 + i] = v;
    }
    __syncthreads();

    // ---- Phase 4: antisymmetrized table Fk[ijkl] = ERI[ijkl] - 0.5*ERI[ikjl] ----
    #pragma unroll
    for (int e0 = 0; e0 < 4; ++e0) {
        int e = lane * 4 + e0;
        int i = (e >> 6) & 3, j = (e >> 4) & 3, k = (e >> 2) & 3, l = e & 3;
        sFk[e] = sERI[e] - 0.5f * sERI[((i * 4 + k) * 4 + j) * 4 + l];
    }
    __syncthreads();

    // ---- Phase 5: lane 0 -- one-time eigh(S), X = S^{-1/2} ----
    if (lane == 0) {
        float A[4][4], Vv[4][4], w4[4];
        #pragma unroll
        for (int i = 0; i < 4; ++i)
            #pragma unroll
            for (int j = 0; j < 4; ++j) A[i][j] = sSm[i * 4 + j];
        eigh4(A, Vv, w4);
        float iw[4];
        #pragma unroll
        for (int m = 0; m < 4; ++m) iw[m] = frsq(w4[m]);
        #pragma unroll
        for (int i = 0; i < 4; ++i)
            #pragma unroll
            for (int j = 0; j < 4; ++j) {
                float s = 0.0f;
                #pragma unroll
                for (int m = 0; m < 4; ++m) s += Vv[i][m] * iw[m] * Vv[j][m];
                sX[i * 4 + j] = s;
            }
    }
    __syncthreads();

    // ---- Phase 6a: Gt[a][b][k][l] = sum_ij X_ia X_jb Fk[ijkl]  (64 lanes x 4) ----
    {
        int t0 = lane * 4;
        int a = (t0 >> 6) & 3, b = (t0 >> 4) & 3;
        float xx[4][4];
        #pragma unroll
        for (int i = 0; i < 4; ++i)
            #pragma unroll
            for (int j = 0; j < 4; ++j) xx[i][j] = sX[i * 4 + a] * sX[j * 4 + b];
        #pragma unroll
        for (int l = 0; l < 4; ++l) {
            float s = 0.0f;
            #pragma unroll
            for (int i = 0; i < 4; ++i)
                #pragma unroll
                for (int j = 0; j < 4; ++j)
                    s += xx[i][j] * sFk[(i * 4 + j) * 16 + (t0 & 15) + l];
            sGt[t0 + l] = s;
        }
    }
    __syncthreads();

    // ---- Phase 6b: GG[p][q] (100 coeffs) + Hcp[10], fully transformed basis ----
    if (lane < 50) {
        #pragma unroll
        for (int e0 = 0; e0 < 2; ++e0) {
            int g = lane * 2 + e0;
            int p = g / 10, q = g - p * 10;
            int a, b, c, d;
            pairAB(p, a, b);
            pairAB(q, c, d);
            float s = 0.0f;
            #pragma unroll
            for (int k = 0; k < 4; ++k)
                #pragma unroll
                for (int l = 0; l < 4; ++l) {
                    float W = sX[k * 4 + c] * sX[l * 4 + d];
                    if (c != d) W += sX[k * 4 + d] * sX[l * 4 + c];
                    s += W * sGt[((a * 4 + b) * 4 + k) * 4 + l];
                }
            sGG[g] = 2.0f * s;
        }
    } else if (lane < 60) {
        int p = lane - 50;
        int a, b;
        pairAB(p, a, b);
        float s = 0.0f;
        #pragma unroll
        for (int i = 0; i < 4; ++i)
            #pragma unroll
            for (int j = 0; j < 4; ++j)
                s += sX[i * 4 + a] * sHc[i * 4 + j] * sX[j * 4 + b];
        sHcp[p] = s;
    }
    __syncthreads();

    // ---- Phase 7: SCF, all 64 lanes cooperating (no divergence) ----
    // Lane p<10 owns GG row p; buildM = per-lane 10-FMA chain + 10 __shfl broadcasts.
    // pstep/gersh/vnorm run redundantly on all lanes.
    {
        int myrow = (lane < 10) ? lane : 0;
        float Gr[10];
        #pragma unroll
        for (int q = 0; q < 10; ++q) Gr[q] = sGG[myrow * 10 + q];
        float Hown = sHcp[myrow];
        float Hr[10];
        #pragma unroll
        for (int p = 0; p < 10; ++p) Hr[p] = sHcp[p];

        float v0, v1, v2, v3;
        float Mp[10];

        auto vnorm = [&]() {
            float nn = v0 * v0 + v1 * v1 + v2 * v2 + v3 * v3;
            float r = frsq(nn);
            v0 *= r; v1 *= r; v2 *= r; v3 *= r;
        };
        auto buildM = [&]() {
            float w0 = v0 * v0, w1 = v0 * v1, w2 = v0 * v2, w3 = v0 * v3;
            float w4 = v1 * v1, w5 = v1 * v2, w6 = v1 * v3;
            float w7 = v2 * v2, w8 = v2 * v3, w9 = v3 * v3;
            float s = Hown;
            s = fmaf(Gr[0], w0, s); s = fmaf(Gr[1], w1, s);
            s = fmaf(Gr[2], w2, s); s = fmaf(Gr[3], w3, s);
            s = fmaf(Gr[4], w4, s); s = fmaf(Gr[5], w5, s);
            s = fmaf(Gr[6], w6, s); s = fmaf(Gr[7], w7, s);
            s = fmaf(Gr[8], w8, s); s = fmaf(Gr[9], w9, s);
            #pragma unroll
            for (int p = 0; p < 10; ++p) Mp[p] = __shfl(s, p);
        };
        auto gersh = [&]() {
            float r0 = Mp[0] + fabsf(Mp[1]) + fabsf(Mp[2]) + fabsf(Mp[3]);
            float r1 = Mp[4] + fabsf(Mp[1]) + fabsf(Mp[5]) + fabsf(Mp[6]);
            float r2 = Mp[7] + fabsf(Mp[2]) + fabsf(Mp[5]) + fabsf(Mp[8]);
            float r3 = Mp[9] + fabsf(Mp[3]) + fabsf(Mp[6]) + fabsf(Mp[8]);
            return fmaxf(fmaxf(r0, r1), fmaxf(r2, r3));
        };
        auto pstep = [&](float sig) {
            float m0 = fmaf(Mp[0], v0, fmaf(Mp[1], v1, fmaf(Mp[2], v2, Mp[3] * v3)));
            float m1 = fmaf(Mp[1], v0, fmaf(Mp[4], v1, fmaf(Mp[5], v2, Mp[6] * v3)));
            float m2 = fmaf(Mp[2], v0, fmaf(Mp[5], v1, fmaf(Mp[7], v2, Mp[8] * v3)));
            float m3 = fmaf(Mp[3], v0, fmaf(Mp[6], v1, fmaf(Mp[8], v2, Mp[9] * v3)));
            v0 = fmaf(sig, v0, -m0);
            v1 = fmaf(sig, v1, -m1);
            v2 = fmaf(sig, v2, -m2);
            v3 = fmaf(sig, v3, -m3);
        };

        // Bootstrap: D=0 -> Fp = Hcp; 12 shifted power iterations (no norms needed,
        // growth ~ (sig-l1)^12 << fp32 range), then normalize.
        #pragma unroll
        for (int p = 0; p < 10; ++p) Mp[p] = Hr[p];
        {
            float dmin = fminf(fminf(Mp[0], Mp[4]), fminf(Mp[7], Mp[9]));
            v0 = (Mp[0] == dmin) ? 1.0f : 0.25f;
            v1 = (Mp[4] == dmin) ? 1.0f : 0.25f;
            v2 = (Mp[7] == dmin) ? 1.0f : 0.25f;
            v3 = (Mp[9] == dmin) ? 1.0f : 0.25f;
            float sig = gersh();
            for (int t = 0; t < 12; ++t) pstep(sig);
        }

        // Main SCF: 12 warm-started steps x 3 power iterations.
        // Energy is stationary in v => quadratic error suppression; huge margin
        // vs the 2.2e-2 threshold.
        for (int it = 0; it < 12; ++it) {
            vnorm();
            buildM();
            float sig = gersh();
            pstep(sig); pstep(sig); pstep(sig);
        }
        vnorm();
        buildM();

        // e_elec = v^T (Hcp + Fp) v, computed redundantly; lane 0 writes.
        float A0 = Hr[0] + Mp[0], A1 = Hr[1] + Mp[1], A2 = Hr[2] + Mp[2];
        float A3 = Hr[3] + Mp[3], A4 = Hr[4] + Mp[4], A5 = Hr[5] + Mp[5];
        float A6 = Hr[6] + Mp[6], A7 = Hr[7] + Mp[7], A8 = Hr[8] + Mp[8];
        float A9 = Hr[9] + Mp[9];
        float e = A0 * v0 * v0 + A4 * v1 * v1 + A7 * v2 * v2 + A9 * v3 * v3
                + 2.0f * (A1 * v0 * v1 + A2 * v0 * v2 + A3 * v0 * v3
                        + A5 * v1 * v2 + A6 * v1 * v3 + A8 * v2 * v3);
        float dx = R[0] - R[3], dy = R[1] - R[4], dz = R[2] - R[5];
        e += frsq(dx * dx + dy * dy + dz * dz);  // Z0*Z1 = 1
        if (lane == 0) out[0] = e;
    }
}

extern "C" void kernel_launch(void* const* d_in, const int* in_sizes, int n_in,
                              void* d_out, int out_size, void* d_ws, size_t ws_size,
                              hipStream_t stream) {
    const float* R = (const float*)d_in[0];
    float* out = (float*)d_out;
    hf_h2_kernel<<<1, 64, 0, stream>>>(R, out);
}

// Round 5
// 15.431 us; speedup vs baseline: 22.4098x; 1.3159x over previous
//
#include <hip/hip_runtime.h>
#include <math.h>

#define PI_F 3.14159265358979323846f

__device__ __constant__ float c_EX[8] = {5.447178f, 0.8245472f, 0.1831916f, 1.0f,
                                         5.447178f, 0.8245472f, 0.1831916f, 1.0f};
// c_CF * (2*EX/pi)^0.75 precomputed in double precision
__device__ __constant__ float c_NC[8] = {0.39715137f, 0.55792070f, 0.19956670f, 0.0f,
                                         0.39715137f, 0.55792070f, 0.19956670f, 0.0f};

__device__ __forceinline__ float frcp(float x) { return __builtin_amdgcn_rcpf(x); }
__device__ __forceinline__ float frsq(float x) { return __builtin_amdgcn_rsqf(x); }

// Boys F0. For t>=0.01: 0.5*sqrt(pi/t)*erf(sqrt(t)) with A&S 7.1.26 erf
// (|err|<=1.5e-7 -> f0 err <=1.3e-6 since sqrt(t)>=0.1). For t<0.01: series
// 1 - t/3 + t^2/10 (err ~ t^3/42 <= 2.4e-8). Matches reference to ~1e-6.
__device__ __forceinline__ float f0f(float tv) {
    float ts = fmaxf(tv, 1e-12f);
    float st = sqrtf(ts);
    float u = frcp(fmaf(0.3275911f, st, 1.0f));
    float c = fmaf(u, 1.061405429f, -1.453152027f);
    c = fmaf(u, c, 1.421413741f);
    c = fmaf(u, c, -0.284496736f);
    c = fmaf(u, c, 0.254829592f);
    float poly = c * u;
    float ex = __expf(-ts);                       // e^{-x^2}, x=sqrt(ts)
    float big = 0.88622692545f * frcp(st) * (1.0f - poly * ex);
    float ser = fmaf(tv, fmaf(tv, 0.1f, -0.3333333333f), 1.0f);
    return (tv < 0.01f) ? ser : big;
}

// (0,0)(0,1)(0,2)(0,3)(1,1)(1,2)(1,3)(2,2)(2,3)(3,3)
__device__ __forceinline__ void pairAB(int p, int& a, int& b) {
    a = (p < 4) ? 0 : ((p < 7) ? 1 : ((p < 9) ? 2 : 3));
    b = p - ((p < 4) ? 0 : ((p < 7) ? 3 : ((p < 9) ? 5 : 6)));
}

#define ROT(p, q) do {                                                          \
    float apq = A[p][q];                                                        \
    float diff = A[q][q] - A[p][p];                                             \
    float theta = 0.5f * diff * frcp(apq);                                      \
    float tt = copysignf(1.0f, theta) * frcp(fabsf(theta) + sqrtf(1.0f + theta * theta)); \
    tt = (apq == 0.0f) ? 0.0f : tt;                                             \
    float cr = frsq(1.0f + tt * tt);                                            \
    float sr = tt * cr;                                                         \
    _Pragma("unroll")                                                           \
    for (int k_ = 0; k_ < 4; ++k_) { float a1 = A[k_][p], a2 = A[k_][q];        \
        A[k_][p] = cr * a1 - sr * a2; A[k_][q] = sr * a1 + cr * a2; }           \
    _Pragma("unroll")                                                           \
    for (int k_ = 0; k_ < 4; ++k_) { float a1 = A[p][k_], a2 = A[q][k_];        \
        A[p][k_] = cr * a1 - sr * a2; A[q][k_] = sr * a1 + cr * a2; }           \
    _Pragma("unroll")                                                           \
    for (int k_ = 0; k_ < 4; ++k_) { float a1 = Vv[k_][p], a2 = Vv[k_][q];      \
        Vv[k_][p] = cr * a1 - sr * a2; Vv[k_][q] = sr * a1 + cr * a2; }         \
} while (0)

__global__ __launch_bounds__(128, 1) void hf_h2_kernel(const float* __restrict__ R,
                                                       float* __restrict__ out) {
    __shared__ float pp[64], pW[64], pPx[64], pPy[64], pPz[64], pcc[64];
    __shared__ float pSp[64], pTp[64], pVp[64];
    __shared__ float sSm[16], sTm[16], sVm[16], sHc[16], sN[4];
    __shared__ float sERI[256], sTa[256], sTb[256];
    __shared__ float sX[16], sGG[100], sHcp[10], sE[55];

    const int t = threadIdx.x;

    // ---- P1: primitive-pair quantities (wave 0) ----
    if (t < 64) {
        int u = t >> 3, v = t & 7;
        float au = c_EX[u], av = c_EX[v];
        float cu = c_NC[u], cv = c_NC[v];
        int atu = (u >> 2) * 3, atv = (v >> 2) * 3;
        float ux = R[atu + 0], uy = R[atu + 1], uz = R[atu + 2];
        float vx = R[atv + 0], vy = R[atv + 1], vz = R[atv + 2];
        float ps = au + av;
        float inv = frcp(ps);
        float mu = au * av * inv;
        float dx = ux - vx, dy = uy - vy, dz = uz - vz;
        float r2 = dx * dx + dy * dy + dz * dz;
        float Kab = __expf(-mu * r2);
        float Px = (au * ux + av * vx) * inv;
        float Py = (au * uy + av * vy) * inv;
        float Pz = (au * uz + av * vz) * inv;
        float pio = PI_F * inv;
        float Sp = pio * sqrtf(pio) * Kab;
        float Tp = mu * (3.0f - 2.0f * mu * r2) * Sp;
        float d0x = Px - R[0], d0y = Py - R[1], d0z = Pz - R[2];
        float d1x = Px - R[3], d1y = Py - R[4], d1z = Pz - R[5];
        float pc0 = d0x * d0x + d0y * d0y + d0z * d0z;
        float pc1 = d1x * d1x + d1y * d1y + d1z * d1z;
        float Vp = -(2.0f * PI_F * inv) * Kab * (f0f(ps * pc0) + f0f(ps * pc1));
        pp[t] = ps; pW[t] = cu * cv * Kab;
        pPx[t] = Px; pPy[t] = Py; pPz[t] = Pz;
        pcc[t] = cu * cv;
        pSp[t] = Sp; pTp[t] = Tp; pVp[t] = Vp;
    }
    __syncthreads();

    // ---- P2a: contracted S,T,V + sN on diagonal lanes ----
    if (t < 16) {
        int i = t >> 2, j = t & 3;
        float aS = 0.0f, aT = 0.0f, aV = 0.0f;
        #pragma unroll
        for (int p = 0; p < 2; ++p)
        #pragma unroll
        for (int q = 0; q < 2; ++q) {
            int b = (i * 2 + p) * 8 + (j * 2 + q);
            float w = pcc[b];
            aS += w * pSp[b]; aT += w * pTp[b]; aV += w * pVp[b];
        }
        sSm[t] = aS; sTm[t] = aT; sVm[t] = aV;
        if (i == j) sN[i] = frsq(aS);
    }
    __syncthreads();

    // ---- P2b: wave 0 = unique ERI (55 lanes, rolled 16-quad loop)
    //          wave 1 = eigh(Snorm) + X = S^{-1/2}  (concurrent on other SIMD) ----
    int ui = 0, uj = 0, uk = 0, ul = 0;
    if (t < 64) {
        int tt = (t < 55) ? t : 0;
        int P = (tt >= 10) + (tt >= 19) + (tt >= 27) + (tt >= 34) + (tt >= 40)
              + (tt >= 45) + (tt >= 49) + (tt >= 52) + (tt >= 54);
        int base = P * 10 - ((P * (P - 1)) >> 1);
        int Q = tt - base + P;
        pairAB(P, ui, uj);
        pairAB(Q, uk, ul);
        float sum = 0.0f;
        #pragma unroll
        for (int n = 0; n < 4; ++n) {
            int p = n >> 1, q = n & 1;
            int b1 = (ui * 2 + p) * 8 + uj * 2 + q;
            float p1 = pp[b1], W1 = pW[b1];
            float x1 = pPx[b1], y1 = pPy[b1], z1 = pPz[b1];
            #pragma unroll 2
            for (int m = 0; m < 4; ++m) {
                int r = m >> 1, s2 = m & 1;
                int b2 = (uk * 2 + r) * 8 + ul * 2 + s2;
                float p2 = pp[b2];
                float psum = p1 + p2;
                float dx = x1 - pPx[b2], dy = y1 - pPy[b2], dz = z1 - pPz[b2];
                float pq2 = dx * dx + dy * dy + dz * dz;
                float p12 = p1 * p2;
                float invs = frsq(psum);
                float al = p12 * invs * invs;
                float gf = 34.98683665f * frcp(p12) * invs;  // 2*pi^2.5 / (p1 p2 sqrt(p1+p2))
                sum += W1 * pW[b2] * gf * f0f(al * pq2);
            }
        }
        if (t < 55) sE[t] = sum;
    } else if (t == 64) {
        float A[4][4], Vv[4][4];
        #pragma unroll
        for (int i = 0; i < 4; ++i)
            #pragma unroll
            for (int j = 0; j < 4; ++j) {
                A[i][j] = sSm[i * 4 + j] * sN[i] * sN[j];
                Vv[i][j] = (i == j) ? 1.0f : 0.0f;
            }
        #pragma unroll 1
        for (int sw = 0; sw < 3; ++sw) {
            ROT(0, 1); ROT(0, 2); ROT(0, 3); ROT(1, 2); ROT(1, 3); ROT(2, 3);
        }
        float iw[4];
        #pragma unroll
        for (int m = 0; m < 4; ++m) iw[m] = frsq(A[m][m]);
        #pragma unroll
        for (int i = 0; i < 4; ++i)
            #pragma unroll
            for (int j = 0; j < 4; ++j) {
                float s = 0.0f;
                #pragma unroll
                for (int m = 0; m < 4; ++m) s += Vv[i][m] * iw[m] * Vv[j][m];
                sX[i * 4 + j] = s;
            }
    }
    __syncthreads();

    // ---- P3: wave 0 scatters normalized ERI; wave 1 normalizes Hc ----
    if (t < 55) {
        float v = sE[t] * sN[ui] * sN[uj] * sN[uk] * sN[ul];
        int i = ui, j = uj, k = uk, l = ul;
        sERI[((i * 4 + j) * 4 + k) * 4 + l] = v;
        sERI[((j * 4 + i) * 4 + k) * 4 + l] = v;
        sERI[((i * 4 + j) * 4 + l) * 4 + k] = v;
        sERI[((j * 4 + i) * 4 + l) * 4 + k] = v;
        sERI[((k * 4 + l) * 4 + i) * 4 + j] = v;
        sERI[((l * 4 + k) * 4 + i) * 4 + j] = v;
        sERI[((k * 4 + l) * 4 + j) * 4 + i] = v;
        sERI[((l * 4 + k) * 4 + j) * 4 + i] = v;
    } else if (t >= 64 && t < 80) {
        int m = t - 64;
        int i = m >> 2, j = m & 3;
        sHc[m] = (sTm[m] + sVm[m]) * sN[i] * sN[j];
    }
    __syncthreads();

    // ---- T1: over i.  T1[a,j,k,l] = sum_i X[i][a] * ERI[i,j,k,l] ----
    #pragma unroll
    for (int z = 0; z < 2; ++z) {
        int e = t + z * 128;
        int a = e >> 6, low = e & 63;
        float s = 0.0f;
        #pragma unroll
        for (int i = 0; i < 4; ++i) s = fmaf(sX[i * 4 + a], sERI[i * 64 + low], s);
        sTa[e] = s;
    }
    __syncthreads();

    // ---- T2: over j.  T2[a,b,k,l] = sum_j X[j][b] * T1[a,j,k,l] ----
    #pragma unroll
    for (int z = 0; z < 2; ++z) {
        int e = t + z * 128;
        int a = e >> 6, b = (e >> 4) & 3, kl = e & 15;
        float s = 0.0f;
        #pragma unroll
        for (int j = 0; j < 4; ++j) s = fmaf(sX[j * 4 + b], sTa[a * 64 + j * 16 + kl], s);
        sTb[e] = s;
    }
    __syncthreads();

    // ---- T3: over k.  T3[a,b,c,l] = sum_k X[k][c] * T2[a,b,k,l] ----
    #pragma unroll
    for (int z = 0; z < 2; ++z) {
        int e = t + z * 128;
        int c = (e >> 2) & 3, base = e & ~15, l = e & 3;
        float s = 0.0f;
        #pragma unroll
        for (int k = 0; k < 4; ++k) s = fmaf(sX[k * 4 + c], sTb[base + k * 4 + l], s);
        sTa[e] = s;
    }
    __syncthreads();

    // ---- T4: over l.  E'[a,b,c,d] = sum_l X[l][d] * T3[a,b,c,l] ----
    #pragma unroll
    for (int z = 0; z < 2; ++z) {
        int e = t + z * 128;
        int d = e & 3, base = e & ~3;
        float s = 0.0f;
        #pragma unroll
        for (int l = 0; l < 4; ++l) s = fmaf(sX[l * 4 + d], sTa[base + l], s);
        sTb[e] = s;
    }
    __syncthreads();

    // ---- GG picks (antisym AFTER transform: H[abcd] = E'[abcd]-0.5E'[acbd]) + Hcp ----
    if (t < 100) {
        int p = t / 10, q = t - p * 10;
        int a, b, c, d;
        pairAB(p, a, b);
        pairAB(q, c, d);
        float H1 = sTb[a * 64 + b * 16 + c * 4 + d] - 0.5f * sTb[a * 64 + c * 16 + b * 4 + d];
        float H2 = sTb[a * 64 + b * 16 + d * 4 + c] - 0.5f * sTb[a * 64 + d * 16 + b * 4 + c];
        sGG[t] = 2.0f * (H1 + ((c != d) ? H2 : 0.0f));
    } else if (t < 110) {
        int p = t - 100;
        int a, b;
        pairAB(p, a, b);
        float s = 0.0f;
        #pragma unroll 1
        for (int m = 0; m < 16; ++m) {
            int i = m >> 2, j = m & 3;
            s = fmaf(sX[i * 4 + a] * sHc[m], sX[j * 4 + b], s);
        }
        sHcp[p] = s;
    }
    __syncthreads();

    // ---- P7: SCF on wave 0 (lane p<10 owns GG row p; shfl broadcast) ----
    if (t < 64) {
        int myrow = (t < 10) ? t : 0;
        float Gr[10];
        #pragma unroll
        for (int q = 0; q < 10; ++q) Gr[q] = sGG[myrow * 10 + q];
        float Hown = sHcp[myrow];
        float Hr[10];
        #pragma unroll
        for (int p = 0; p < 10; ++p) Hr[p] = sHcp[p];

        float v0, v1, v2, v3;
        float Mp[10];

        auto vnorm = [&]() {
            float nn = v0 * v0 + v1 * v1 + v2 * v2 + v3 * v3;
            float r = frsq(nn);
            v0 *= r; v1 *= r; v2 *= r; v3 *= r;
        };
        auto buildM = [&]() {
            float w0 = v0 * v0, w1 = v0 * v1, w2 = v0 * v2, w3 = v0 * v3;
            float w4 = v1 * v1, w5 = v1 * v2, w6 = v1 * v3;
            float w7 = v2 * v2, w8 = v2 * v3, w9 = v3 * v3;
            float s = Hown;
            s = fmaf(Gr[0], w0, s); s = fmaf(Gr[1], w1, s);
            s = fmaf(Gr[2], w2, s); s = fmaf(Gr[3], w3, s);
            s = fmaf(Gr[4], w4, s); s = fmaf(Gr[5], w5, s);
            s = fmaf(Gr[6], w6, s); s = fmaf(Gr[7], w7, s);
            s = fmaf(Gr[8], w8, s); s = fmaf(Gr[9], w9, s);
            #pragma unroll
            for (int p = 0; p < 10; ++p) Mp[p] = __shfl(s, p);
        };
        auto gersh = [&]() {
            float r0 = Mp[0] + fabsf(Mp[1]) + fabsf(Mp[2]) + fabsf(Mp[3]);
            float r1 = Mp[4] + fabsf(Mp[1]) + fabsf(Mp[5]) + fabsf(Mp[6]);
            float r2 = Mp[7] + fabsf(Mp[2]) + fabsf(Mp[5]) + fabsf(Mp[8]);
            float r3 = Mp[9] + fabsf(Mp[3]) + fabsf(Mp[6]) + fabsf(Mp[8]);
            return fmaxf(fmaxf(r0, r1), fmaxf(r2, r3));
        };
        auto pstep = [&](float sig) {
            float m0 = fmaf(Mp[0], v0, fmaf(Mp[1], v1, fmaf(Mp[2], v2, Mp[3] * v3)));
            float m1 = fmaf(Mp[1], v0, fmaf(Mp[4], v1, fmaf(Mp[5], v2, Mp[6] * v3)));
            float m2 = fmaf(Mp[2], v0, fmaf(Mp[5], v1, fmaf(Mp[7], v2, Mp[8] * v3)));
            float m3 = fmaf(Mp[3], v0, fmaf(Mp[6], v1, fmaf(Mp[8], v2, Mp[9] * v3)));
            v0 = fmaf(sig, v0, -m0);
            v1 = fmaf(sig, v1, -m1);
            v2 = fmaf(sig, v2, -m2);
            v3 = fmaf(sig, v3, -m3);
        };

        // Bootstrap: Fp = Hcp, 12 shifted power iterations.
        #pragma unroll
        for (int p = 0; p < 10; ++p) Mp[p] = Hr[p];
        {
            float dmin = fminf(fminf(Mp[0], Mp[4]), fminf(Mp[7], Mp[9]));
            v0 = (Mp[0] == dmin) ? 1.0f : 0.25f;
            v1 = (Mp[4] == dmin) ? 1.0f : 0.25f;
            v2 = (Mp[7] == dmin) ? 1.0f : 0.25f;
            v3 = (Mp[9] == dmin) ? 1.0f : 0.25f;
            float sig = gersh();
            #pragma unroll 1
            for (int it = 0; it < 12; ++it) pstep(sig);
        }

        // Main SCF: 12 warm-started steps x 3 power iterations.
        #pragma unroll 1
        for (int it = 0; it < 12; ++it) {
            vnorm();
            buildM();
            float sig = gersh();
            pstep(sig); pstep(sig); pstep(sig);
        }
        vnorm();
        buildM();

        float A0 = Hr[0] + Mp[0], A1 = Hr[1] + Mp[1], A2 = Hr[2] + Mp[2];
        float A3 = Hr[3] + Mp[3], A4 = Hr[4] + Mp[4], A5 = Hr[5] + Mp[5];
        float A6 = Hr[6] + Mp[6], A7 = Hr[7] + Mp[7], A8 = Hr[8] + Mp[8];
        float A9 = Hr[9] + Mp[9];
        float e = A0 * v0 * v0 + A4 * v1 * v1 + A7 * v2 * v2 + A9 * v3 * v3
                + 2.0f * (A1 * v0 * v1 + A2 * v0 * v2 + A3 * v0 * v3
                        + A5 * v1 * v2 + A6 * v1 * v3 + A8 * v2 * v3);
        float dx = R[0] - R[3], dy = R[1] - R[4], dz = R[2] - R[5];
        e += frsq(dx * dx + dy * dy + dz * dz);  // Z0*Z1 = 1
        if (t == 0) out[0] = e;
    }
}

extern "C" void kernel_launch(void* const* d_in, const int* in_sizes, int n_in,
                              void* d_out, int out_size, void* d_ws, size_t ws_size,
                              hipStream_t stream) {
    const float* R = (const float*)d_in[0];
    float* out = (float*)d_out;
    hf_h2_kernel<<<1, 128, 0, stream>>>(R, out);
}

// Round 6
// 9.848 us; speedup vs baseline: 35.1146x; 1.5669x over previous
//
#include <hip/hip_runtime.h>
#include <math.h>

#define PI_F 3.14159265358979323846f

__device__ __constant__ float c_EX[8] = {5.447178f, 0.8245472f, 0.1831916f, 1.0f,
                                         5.447178f, 0.8245472f, 0.1831916f, 1.0f};
// c_CF * (2*EX/pi)^0.75 precomputed in double precision
__device__ __constant__ float c_NC[8] = {0.39715137f, 0.55792070f, 0.19956670f, 0.0f,
                                         0.39715137f, 0.55792070f, 0.19956670f, 0.0f};

__device__ __forceinline__ float frcp(float x) { return __builtin_amdgcn_rcpf(x); }
__device__ __forceinline__ float frsq(float x) { return __builtin_amdgcn_rsqf(x); }

// Boys F0. t>=0.01: 0.5*sqrt(pi/t)*erf(sqrt(t)) with A&S 7.1.26 erf (|err|<=1.5e-7).
// t<0.01: series 1 - t/3 + t^2/10. Total err ~1e-6 << 2.2e-2 threshold.
__device__ __forceinline__ float f0f(float tv) {
    float ts = fmaxf(tv, 1e-12f);
    float st = sqrtf(ts);
    float u = frcp(fmaf(0.3275911f, st, 1.0f));
    float c = fmaf(u, 1.061405429f, -1.453152027f);
    c = fmaf(u, c, 1.421413741f);
    c = fmaf(u, c, -0.284496736f);
    c = fmaf(u, c, 0.254829592f);
    float poly = c * u;
    float ex = __expf(-ts);
    float big = 0.88622692545f * frcp(st) * (1.0f - poly * ex);
    float ser = fmaf(tv, fmaf(tv, 0.1f, -0.3333333333f), 1.0f);
    return (tv < 0.01f) ? ser : big;
}

// (0,0)(0,1)(0,2)(0,3)(1,1)(1,2)(1,3)(2,2)(2,3)(3,3)
__device__ __forceinline__ void pairAB(int p, int& a, int& b) {
    a = (p < 4) ? 0 : ((p < 7) ? 1 : ((p < 9) ? 2 : 3));
    b = p - ((p < 4) ? 0 : ((p < 7) ? 3 : ((p < 9) ? 5 : 6)));
}

__global__ __launch_bounds__(128, 1) void hf_h2_kernel(const float* __restrict__ R,
                                                       float* __restrict__ out) {
    __shared__ float pp[64], pW[64], pPx[64], pPy[64], pPz[64];
    __shared__ float pSp[64], pTp[64], pVp[64];
    __shared__ float sSm[16], sTm[16], sVm[16], sN[4], sHc[16];
    __shared__ float sE2[110], sERI[256], sTa[128], sTb[48];
    __shared__ float sU[4], sT6[6], sHp[3];

    const int t = threadIdx.x;

    // ---- P1: primitive-pair quantities (wave 0). S/T/V prims premultiplied by cc. ----
    if (t < 64) {
        int u = t >> 3, v = t & 7;
        float au = c_EX[u], av = c_EX[v];
        float cc = c_NC[u] * c_NC[v];
        int atu = (u >> 2) * 3, atv = (v >> 2) * 3;
        float ux = R[atu + 0], uy = R[atu + 1], uz = R[atu + 2];
        float vx = R[atv + 0], vy = R[atv + 1], vz = R[atv + 2];
        float ps = au + av;
        float inv = frcp(ps);
        float mu = au * av * inv;
        float dx = ux - vx, dy = uy - vy, dz = uz - vz;
        float r2 = dx * dx + dy * dy + dz * dz;
        float Kab = __expf(-mu * r2);
        float Px = (au * ux + av * vx) * inv;
        float Py = (au * uy + av * vy) * inv;
        float Pz = (au * uz + av * vz) * inv;
        float pio = PI_F * inv;
        float Sp = pio * sqrtf(pio) * Kab;
        float Tp = mu * (3.0f - 2.0f * mu * r2) * Sp;
        float d0x = Px - R[0], d0y = Py - R[1], d0z = Pz - R[2];
        float d1x = Px - R[3], d1y = Py - R[4], d1z = Pz - R[5];
        float pc0 = d0x * d0x + d0y * d0y + d0z * d0z;
        float pc1 = d1x * d1x + d1y * d1y + d1z * d1z;
        float Vp = -(2.0f * PI_F * inv) * Kab * (f0f(ps * pc0) + f0f(ps * pc1));
        pp[t] = ps; pW[t] = cc * Kab;
        pPx[t] = Px; pPy[t] = Py; pPz[t] = Pz;
        pSp[t] = cc * Sp; pTp[t] = cc * Tp; pVp[t] = cc * Vp;
    }
    __syncthreads();

    // ---- P2: unique-ERI halves on 110 lanes (8 quads each) + S/T/V on lanes 110-125 ----
    int ui = 0, uj = 0, uk = 0, ul = 0;
    if (t < 110) {
        int tt = (t < 55) ? t : t - 55;
        int P = (tt >= 10) + (tt >= 19) + (tt >= 27) + (tt >= 34) + (tt >= 40)
              + (tt >= 45) + (tt >= 49) + (tt >= 52) + (tt >= 54);
        int base = P * 10 - ((P * (P - 1)) >> 1);
        int Q = tt - base + P;
        pairAB(P, ui, uj);
        pairAB(Q, uk, ul);
        int nbase = (t >= 55) ? 2 : 0;
        float sum = 0.0f;
        #pragma unroll
        for (int nn = 0; nn < 2; ++nn) {
            int n = nbase + nn;
            int p = n >> 1, q = n & 1;
            int b1 = (ui * 2 + p) * 8 + uj * 2 + q;
            float p1 = pp[b1], W1 = pW[b1];
            float x1 = pPx[b1], y1 = pPy[b1], z1 = pPz[b1];
            #pragma unroll 2
            for (int m = 0; m < 4; ++m) {
                int r = m >> 1, s2 = m & 1;
                int b2 = (uk * 2 + r) * 8 + ul * 2 + s2;
                float p2 = pp[b2];
                float psum = p1 + p2;
                float dx = x1 - pPx[b2], dy = y1 - pPy[b2], dz = z1 - pPz[b2];
                float pq2 = dx * dx + dy * dy + dz * dz;
                float p12 = p1 * p2;
                float invs = frsq(psum);
                float al = p12 * invs * invs;
                float gf = 34.98683665f * frcp(p12) * invs;  // 2*pi^2.5/(p1 p2 sqrt(p1+p2))
                sum += W1 * pW[b2] * gf * f0f(al * pq2);
            }
        }
        sE2[t] = sum;
    } else if (t < 126) {
        int m = t - 110;
        int i = m >> 2, j = m & 3;
        float aS = 0.0f, aT = 0.0f, aV = 0.0f;
        #pragma unroll
        for (int p = 0; p < 2; ++p)
        #pragma unroll
        for (int q = 0; q < 2; ++q) {
            int b = (i * 2 + p) * 8 + (j * 2 + q);
            aS += pSp[b]; aT += pTp[b]; aV += pVp[b];
        }
        sSm[m] = aS; sTm[m] = aT; sVm[m] = aV;
        if (i == j) sN[i] = frsq(aS);
    }
    __syncthreads();

    // ---- P3: combine+normalize+scatter ERI | normalize Hc | closed-form W+ ----
    if (t < 55) {
        float v = (sE2[t] + sE2[t + 55]) * sN[ui] * sN[uj] * sN[uk] * sN[ul];
        int i = ui, j = uj, k = uk, l = ul;
        sERI[((i * 4 + j) * 4 + k) * 4 + l] = v;
        sERI[((j * 4 + i) * 4 + k) * 4 + l] = v;
        sERI[((i * 4 + j) * 4 + l) * 4 + k] = v;
        sERI[((j * 4 + i) * 4 + l) * 4 + k] = v;
        sERI[((k * 4 + l) * 4 + i) * 4 + j] = v;
        sERI[((l * 4 + k) * 4 + i) * 4 + j] = v;
        sERI[((k * 4 + l) * 4 + j) * 4 + i] = v;
        sERI[((l * 4 + k) * 4 + j) * 4 + i] = v;
    } else if (t >= 64 && t < 80) {
        int m = t - 64;
        int i = m >> 2, j = m & 3;
        sHc[m] = (sTm[m] + sVm[m]) * sN[i] * sN[j];
    } else if (t >= 96 && t < 100) {
        // Homonuclear symmetry: S = [[A,B],[B,A]]; + sector overlap M+ = A+B (2x2).
        // W+ = (2 M+)^{-1/2} closed form; y_m[i] = W+[i&1][m] (same on both atoms).
        float n0 = sN[0], n1 = sN[1], n2 = sN[2], n3 = sN[3];
        float a = sSm[1] * n0 * n1;                           // on-atom S01
        float b = sSm[2] * n0 * n2;                           // S02
        float cb = 0.5f * (sSm[3] * n0 * n3 + sSm[6] * n1 * n2);  // S03 = S12
        float d = sSm[7] * n1 * n3;                           // S13
        float p2 = 2.0f * (1.0f + b), q2 = 2.0f * (1.0f + d), r2 = 2.0f * (a + cb);
        float h = 0.5f * (p2 - q2);
        float mm = 0.5f * (p2 + q2);
        float rt = fmaxf(sqrtf(fmaf(h, h, r2 * r2)), 1e-20f);
        float i1 = frsq(mm + rt), i2 = frsq(mm - rt);
        float irt = frcp(rt);
        float c2f = 0.5f * fmaf(h, irt, 1.0f);
        float s2f = 0.5f * fmaf(-h, irt, 1.0f);
        float csf = 0.5f * r2 * irt;
        int idx = t - 96;   // sU[i*2+m], i,m in {0,1}
        float val = (idx == 0) ? (c2f * i1 + s2f * i2)
                  : (idx == 3) ? (s2f * i1 + c2f * i2)
                               : (csf * (i1 - i2));
        sU[idx] = val;
    }
    __syncthreads();

    // ---- P4: T1[m][j][k][l] = sum_i y_m[i] * ERI[ijkl]  (128 entries) ----
    {
        int m = t >> 6, low = t & 63;
        float s = 0.0f;
        #pragma unroll
        for (int i = 0; i < 4; ++i)
            s = fmaf(sU[(i & 1) * 2 + m], sERI[i * 64 + low], s);
        sTa[t] = s;
    }
    __syncthreads();

    // ---- P5: T2[p][k][l], p=(m,n) in {(0,0),(0,1),(1,1)}  (48 entries) ----
    if (t < 48) {
        int p = t >> 4, kl = t & 15;
        int m = p >> 1, n = (p + 1) >> 1;
        float s = 0.0f;
        #pragma unroll
        for (int j = 0; j < 4; ++j)
            s = fmaf(sU[(j & 1) * 2 + n], sTa[m * 64 + j * 16 + kl], s);
        sTb[t] = s;
    }
    __syncthreads();

    // ---- P6: 6 unique fully-transformed ERIs + 3 Hp entries ----
    if (t < 6) {
        int P = (t < 3) ? 0 : ((t < 5) ? 1 : 2);
        int Q = t - ((t < 3) ? 0 : ((t < 5) ? 2 : 3));
        int a = Q >> 1, b = (Q + 1) >> 1;
        float s = 0.0f;
        #pragma unroll
        for (int k = 0; k < 4; ++k) {
            float inner = 0.0f;
            #pragma unroll
            for (int l = 0; l < 4; ++l)
                inner = fmaf(sU[(l & 1) * 2 + b], sTb[P * 16 + k * 4 + l], inner);
            s = fmaf(sU[(k & 1) * 2 + a], inner, s);
        }
        sT6[t] = s;
    } else if (t >= 8 && t < 11) {
        int p = t - 8;
        int a = p >> 1, b = (p + 1) >> 1;
        float s = 0.0f;
        #pragma unroll
        for (int i = 0; i < 4; ++i) {
            float inner = 0.0f;
            #pragma unroll
            for (int j = 0; j < 4; ++j)
                inner = fmaf(sU[(j & 1) * 2 + b], sHc[i * 4 + j], inner);
            s = fmaf(sU[(i & 1) * 2 + a], inner, s);
        }
        sHp[p] = s;
    }
    __syncthreads();

    // ---- P7: 2x2 SCF with exact closed-form lowest eigenvector per step ----
    // F+ = H+ + GS * (v1^2, v1*v2, v2^2); 10 exact steps == ref's 30 (same map).
    {
        float T0 = sT6[0], T1v = sT6[1], T2v = sT6[2];
        float T3v = sT6[3], T4v = sT6[4], T5v = sT6[5];
        float H0 = sHp[0], H1 = sHp[1], H2 = sHp[2];
        float G00 = T0,              G01 = 2.0f * T1v,      G02 = 2.0f * T2v - T3v;
        float G10 = T1v,             G11 = 3.0f * T3v - T2v, G12 = T4v;
        float G20 = G02,             G21 = 2.0f * T4v,      G22 = T5v;

        float f0 = H0, f1 = H1, f2 = H2;
        float w0 = 0.0f, w1 = 0.0f, w2 = 0.0f;
        #pragma unroll 1
        for (int it = 0; it < 10; ++it) {
            float h = 0.5f * (f0 - f2);
            float rt = sqrtf(fmaf(h, h, f1 * f1));
            float va = (h >= 0.0f) ? f1 : (h - rt);
            float vb = (h >= 0.0f) ? (-(h + rt)) : f1;
            float rn = frsq(fmaf(va, va, vb * vb));
            float v1 = va * rn, v2 = vb * rn;
            w0 = v1 * v1; w1 = v1 * v2; w2 = v2 * v2;
            f0 = fmaf(G00, w0, fmaf(G01, w1, fmaf(G02, w2, H0)));
            f1 = fmaf(G10, w0, fmaf(G11, w1, fmaf(G12, w2, H1)));
            f2 = fmaf(G20, w0, fmaf(G21, w1, fmaf(G22, w2, H2)));
        }
        float e = (H0 + f0) * w0 + 2.0f * (H1 + f1) * w1 + (H2 + f2) * w2;
        float dx = R[0] - R[3], dy = R[1] - R[4], dz = R[2] - R[5];
        e += frsq(dx * dx + dy * dy + dz * dz);  // Z0*Z1 = 1
        if (t == 0) out[0] = e;
    }
}

extern "C" void kernel_launch(void* const* d_in, const int* in_sizes, int n_in,
                              void* d_out, int out_size, void* d_ws, size_t ws_size,
                              hipStream_t stream) {
    const float* R = (const float*)d_in[0];
    float* out = (float*)d_out;
    hf_h2_kernel<<<1, 128, 0, stream>>>(R, out);
}

// Round 7
// 9.290 us; speedup vs baseline: 37.2239x; 1.0601x over previous
//
#include <hip/hip_runtime.h>
#include <math.h>

#define PI_F 3.14159265358979323846f

__device__ __constant__ float c_EX[8] = {5.447178f, 0.8245472f, 0.1831916f, 1.0f,
                                         5.447178f, 0.8245472f, 0.1831916f, 1.0f};
// c_CF * (2*EX/pi)^0.75 precomputed in double precision
__device__ __constant__ float c_NC[8] = {0.39715137f, 0.55792070f, 0.19956670f, 0.0f,
                                         0.39715137f, 0.55792070f, 0.19956670f, 0.0f};

__device__ __forceinline__ float frcp(float x) { return __builtin_amdgcn_rcpf(x); }
__device__ __forceinline__ float frsq(float x) { return __builtin_amdgcn_rsqf(x); }

// Boys F0. t>=0.01: 0.5*sqrt(pi/t)*erf(sqrt(t)) with A&S 7.1.26 erf (|err|<=1.5e-7).
// t<0.01: series 1 - t/3 + t^2/10. Total err ~1e-6 << 2.2e-2 threshold.
__device__ __forceinline__ float f0f(float tv) {
    float ts = fmaxf(tv, 1e-12f);
    float st = sqrtf(ts);
    float u = frcp(fmaf(0.3275911f, st, 1.0f));
    float c = fmaf(u, 1.061405429f, -1.453152027f);
    c = fmaf(u, c, 1.421413741f);
    c = fmaf(u, c, -0.284496736f);
    c = fmaf(u, c, 0.254829592f);
    float poly = c * u;
    float ex = __expf(-ts);
    float big = 0.88622692545f * frcp(st) * (1.0f - poly * ex);
    float ser = fmaf(tv, fmaf(tv, 0.1f, -0.3333333333f), 1.0f);
    return (tv < 0.01f) ? ser : big;
}

// (0,0)(0,1)(0,2)(0,3)(1,1)(1,2)(1,3)(2,2)(2,3)(3,3)
__device__ __forceinline__ void pairAB(int p, int& a, int& b) {
    a = (p < 4) ? 0 : ((p < 7) ? 1 : ((p < 9) ? 2 : 3));
    b = p - ((p < 4) ? 0 : ((p < 7) ? 3 : ((p < 9) ? 5 : 6)));
}

__global__ __launch_bounds__(256, 1) void hf_h2_kernel(const float* __restrict__ R,
                                                       float* __restrict__ out) {
    __shared__ float pp[64], pW[64], pPx[64], pPy[64], pPz[64];
    __shared__ float pSp[64], pTp[64], pVp[64];
    __shared__ float sSm[16], sTm[16], sVm[16], sN[4], sHc[16];
    __shared__ float sE4[220], sERI[256];
    __shared__ float sU[4], sEr[16], sHr[4], sT6[6], sHp[3];

    const int t = threadIdx.x;
    const int w = t >> 6;      // wave index 0..3
    const int tt = t & 63;

    // ---- P1: primitive-pair quantities (wave 0). S/T/V prims premultiplied by cc. ----
    if (t < 64) {
        int u = t >> 3, v = t & 7;
        float au = c_EX[u], av = c_EX[v];
        float cc = c_NC[u] * c_NC[v];
        int atu = (u >> 2) * 3, atv = (v >> 2) * 3;
        float ux = R[atu + 0], uy = R[atu + 1], uz = R[atu + 2];
        float vx = R[atv + 0], vy = R[atv + 1], vz = R[atv + 2];
        float ps = au + av;
        float inv = frcp(ps);
        float mu = au * av * inv;
        float dx = ux - vx, dy = uy - vy, dz = uz - vz;
        float r2 = dx * dx + dy * dy + dz * dz;
        float Kab = __expf(-mu * r2);
        float Px = (au * ux + av * vx) * inv;
        float Py = (au * uy + av * vy) * inv;
        float Pz = (au * uz + av * vz) * inv;
        float pio = PI_F * inv;
        float Sp = pio * sqrtf(pio) * Kab;
        float Tp = mu * (3.0f - 2.0f * mu * r2) * Sp;
        float d0x = Px - R[0], d0y = Py - R[1], d0z = Pz - R[2];
        float d1x = Px - R[3], d1y = Py - R[4], d1z = Pz - R[5];
        float pc0 = d0x * d0x + d0y * d0y + d0z * d0z;
        float pc1 = d1x * d1x + d1y * d1y + d1z * d1z;
        float Vp = -(2.0f * PI_F * inv) * Kab * (f0f(ps * pc0) + f0f(ps * pc1));
        pp[t] = ps; pW[t] = cc * Kab;
        pPx[t] = Px; pPy[t] = Py; pPz[t] = Pz;
        pSp[t] = cc * Sp; pTp[t] = cc * Tp; pVp[t] = cc * Vp;
    }
    __syncthreads();

    // ---- P2: unique-ERI quarters on 220 lanes (4 quads each; wave = (p,q) chunk)
    //          + contracted S/T/V on 16 of the tt>=55 lanes ----
    int ui = 0, uj = 0, uk = 0, ul = 0;
    if (tt < 55) {
        int P = (tt >= 10) + (tt >= 19) + (tt >= 27) + (tt >= 34) + (tt >= 40)
              + (tt >= 45) + (tt >= 49) + (tt >= 52) + (tt >= 54);
        int base = P * 10 - ((P * (P - 1)) >> 1);
        int Q = tt - base + P;
        pairAB(P, ui, uj);
        pairAB(Q, uk, ul);
        int p = w >> 1, q = w & 1;
        int b1 = (ui * 2 + p) * 8 + uj * 2 + q;
        float p1 = pp[b1], W1 = pW[b1];
        float x1 = pPx[b1], y1 = pPy[b1], z1 = pPz[b1];
        float sum = 0.0f;
        #pragma unroll 2
        for (int m = 0; m < 4; ++m) {
            int r = m >> 1, s2 = m & 1;
            int b2 = (uk * 2 + r) * 8 + ul * 2 + s2;
            float p2 = pp[b2];
            float psum = p1 + p2;
            float dx = x1 - pPx[b2], dy = y1 - pPy[b2], dz = z1 - pPz[b2];
            float pq2 = dx * dx + dy * dy + dz * dz;
            float p12 = p1 * p2;
            float invs = frsq(psum);
            float al = p12 * invs * invs;
            float gf = 34.98683665f * frcp(p12) * invs;  // 2*pi^2.5/(p1 p2 sqrt(p1+p2))
            sum += W1 * pW[b2] * gf * f0f(al * pq2);
        }
        sE4[w * 55 + tt] = sum;
    } else {
        int m = w * 9 + (tt - 55);   // 0..35
        if (m < 16) {
            int i = m >> 2, j = m & 3;
            float aS = 0.0f, aT = 0.0f, aV = 0.0f;
            #pragma unroll
            for (int p = 0; p < 2; ++p)
            #pragma unroll
            for (int q = 0; q < 2; ++q) {
                int b = (i * 2 + p) * 8 + (j * 2 + q);
                aS += pSp[b]; aT += pTp[b]; aV += pVp[b];
            }
            sSm[m] = aS; sTm[m] = aT; sVm[m] = aV;
            if (i == j) sN[i] = frsq(aS);
        }
    }
    __syncthreads();

    // ---- P3: combine+normalize+scatter ERI | normalize Hc | closed-form W+ ----
    if (t < 55) {
        // ui..ul still live in registers from P2 (wave 0, tt==t)
        float v = (sE4[t] + sE4[55 + t] + sE4[110 + t] + sE4[165 + t])
                * sN[ui] * sN[uj] * sN[uk] * sN[ul];
        int i = ui, j = uj, k = uk, l = ul;
        sERI[((i * 4 + j) * 4 + k) * 4 + l] = v;
        sERI[((j * 4 + i) * 4 + k) * 4 + l] = v;
        sERI[((i * 4 + j) * 4 + l) * 4 + k] = v;
        sERI[((j * 4 + i) * 4 + l) * 4 + k] = v;
        sERI[((k * 4 + l) * 4 + i) * 4 + j] = v;
        sERI[((l * 4 + k) * 4 + i) * 4 + j] = v;
        sERI[((k * 4 + l) * 4 + j) * 4 + i] = v;
        sERI[((l * 4 + k) * 4 + j) * 4 + i] = v;
    } else if (t >= 64 && t < 80) {
        int m = t - 64;
        int i = m >> 2, j = m & 3;
        sHc[m] = (sTm[m] + sVm[m]) * sN[i] * sN[j];
    } else if (t >= 96 && t < 100) {
        // Homonuclear symmetry: + sector overlap M+ = A+B (2x2);
        // W+ = (2 M+)^{-1/2} closed form; y_m[i] = sU[(i&1)*2+m] for all i.
        float n0 = sN[0], n1 = sN[1], n2 = sN[2], n3 = sN[3];
        float a = sSm[1] * n0 * n1;                               // on-atom S01
        float b = sSm[2] * n0 * n2;                               // S02
        float cb = 0.5f * (sSm[3] * n0 * n3 + sSm[6] * n1 * n2);  // S03 = S12
        float d = sSm[7] * n1 * n3;                               // S13
        float p2 = 2.0f * (1.0f + b), q2 = 2.0f * (1.0f + d), r2 = 2.0f * (a + cb);
        float h = 0.5f * (p2 - q2);
        float mm = 0.5f * (p2 + q2);
        float rt = fmaxf(sqrtf(fmaf(h, h, r2 * r2)), 1e-20f);
        float i1 = frsq(mm + rt), i2 = frsq(mm - rt);
        float irt = frcp(rt);
        float c2f = 0.5f * fmaf(h, irt, 1.0f);
        float s2f = 0.5f * fmaf(-h, irt, 1.0f);
        float csf = 0.5f * r2 * irt;
        int idx = t - 96;   // sU[alpha*2+m]
        float val = (idx == 0) ? (c2f * i1 + s2f * i2)
                  : (idx == 3) ? (s2f * i1 + c2f * i2)
                               : (csf * (i1 - i2));
        sU[idx] = val;
    }
    __syncthreads();

    // ---- P4: parity-class reductions.  Ered[16] and Hred[4] ----
    if (t < 16) {
        int al = (t >> 3) & 1, be = (t >> 2) & 1, ga = (t >> 1) & 1, de = t & 1;
        float s = 0.0f;
        #pragma unroll
        for (int i2 = 0; i2 < 2; ++i2)
        #pragma unroll
        for (int j2 = 0; j2 < 2; ++j2)
        #pragma unroll
        for (int k2 = 0; k2 < 2; ++k2)
        #pragma unroll
        for (int l2 = 0; l2 < 2; ++l2)
            s += sERI[((al + 2 * i2) * 4 + (be + 2 * j2)) * 16
                      + (ga + 2 * k2) * 4 + (de + 2 * l2)];
        sEr[t] = s;
    } else if (t < 20) {
        int c = t - 16;
        int al = (c >> 1) & 1, be = c & 1;
        sHr[c] = sHc[al * 4 + be] + sHc[al * 4 + be + 2]
               + sHc[(al + 2) * 4 + be] + sHc[(al + 2) * 4 + be + 2];
    }
    __syncthreads();

    // ---- P5: 6 fully-transformed ERIs + 3 Hp entries from parity classes ----
    if (t < 6) {
        int P = (t < 3) ? 0 : ((t < 5) ? 1 : 2);
        int Q = t - ((t < 3) ? 0 : ((t < 5) ? 2 : 3));
        int a = P >> 1, b = (P + 1) >> 1, c = Q >> 1, d = (Q + 1) >> 1;
        float s = 0.0f;
        #pragma unroll
        for (int al = 0; al < 2; ++al)
        #pragma unroll
        for (int be = 0; be < 2; ++be) {
            float L = sU[al * 2 + a] * sU[be * 2 + b];
            #pragma unroll
            for (int ga = 0; ga < 2; ++ga)
            #pragma unroll
            for (int de = 0; de < 2; ++de)
                s = fmaf(L * (sU[ga * 2 + c] * sU[de * 2 + d]),
                         sEr[al * 8 + be * 4 + ga * 2 + de], s);
        }
        sT6[t] = s;
    } else if (t >= 8 && t < 11) {
        int p = t - 8;
        int a = p >> 1, b = (p + 1) >> 1;
        float s = 0.0f;
        #pragma unroll
        for (int al = 0; al < 2; ++al)
        #pragma unroll
        for (int be = 0; be < 2; ++be)
            s = fmaf(sU[al * 2 + a] * sU[be * 2 + b], sHr[al * 2 + be], s);
        sHp[p] = s;
    }
    __syncthreads();

    // ---- P6: 2x2 SCF with exact closed-form lowest eigenvector per step ----
    {
        float T0 = sT6[0], T1v = sT6[1], T2v = sT6[2];
        float T3v = sT6[3], T4v = sT6[4], T5v = sT6[5];
        float H0 = sHp[0], H1 = sHp[1], H2 = sHp[2];
        float G00 = T0,   G01 = 2.0f * T1v,       G02 = 2.0f * T2v - T3v;
        float G10 = T1v,  G11 = 3.0f * T3v - T2v, G12 = T4v;
        float G20 = G02,  G21 = 2.0f * T4v,       G22 = T5v;

        float f0 = H0, f1 = H1, f2 = H2;
        float w0 = 0.0f, w1 = 0.0f, w2 = 0.0f;
        #pragma unroll 1
        for (int it = 0; it < 10; ++it) {
            float h = 0.5f * (f0 - f2);
            float rt = sqrtf(fmaf(h, h, f1 * f1));
            float va = (h >= 0.0f) ? f1 : (h - rt);
            float vb = (h >= 0.0f) ? (-(h + rt)) : f1;
            float rn = frsq(fmaf(va, va, vb * vb));
            float v1 = va * rn, v2 = vb * rn;
            w0 = v1 * v1; w1 = v1 * v2; w2 = v2 * v2;
            f0 = fmaf(G00, w0, fmaf(G01, w1, fmaf(G02, w2, H0)));
            f1 = fmaf(G10, w0, fmaf(G11, w1, fmaf(G12, w2, H1)));
            f2 = fmaf(G20, w0, fmaf(G21, w1, fmaf(G22, w2, H2)));
        }
        float e = (H0 + f0) * w0 + 2.0f * (H1 + f1) * w1 + (H2 + f2) * w2;
        float dx = R[0] - R[3], dy = R[1] - R[4], dz = R[2] - R[5];
        e += frsq(dx * dx + dy * dy + dz * dz);  // Z0*Z1 = 1
        if (t == 0) out[0] = e;
    }
}

extern "C" void kernel_launch(void* const* d_in, const int* in_sizes, int n_in,
                              void* d_out, int out_size, void* d_ws, size_t ws_size,
                              hipStream_t stream) {
    const float* R = (const float*)d_in[0];
    float* out = (float*)d_out;
    hf_h2_kernel<<<1, 256, 0, stream>>>(R, out);
}